// Round 1
// baseline (3356.693 us; speedup 1.0000x reference)
//
#include <hip/hip_runtime.h>
#include <hip/hip_bf16.h>

// Problem constants: B=4, T=2048, D=1024, L=512, H=8, Lh=64, Dh=128
// n = b*T + t flattens [B,T]; all projection buffers are [n, cols] row-major.

#define BM 64
#define BN 64
#define BK 16

// C[M,N] = A[M,K] @ B[K,N], fp32, all dims multiples of 64/16 (no bounds checks).
__global__ __launch_bounds__(256) void sgemm_kernel(const float* __restrict__ A,
                                                    const float* __restrict__ B,
                                                    float* __restrict__ C,
                                                    int M, int N, int K) {
    __shared__ float As[BK][BM];
    __shared__ float Bs[BK][BN];
    int tid = threadIdx.x;
    int tx = tid & 15, ty = tid >> 4;
    int row0 = blockIdx.y * BM;
    int col0 = blockIdx.x * BN;
    float acc[4][4] = {};
    int arow = tid >> 2;        // 0..63
    int ak   = (tid & 3) * 4;   // 0,4,8,12
    int brow = tid >> 4;        // 0..15
    int bcol = (tid & 15) * 4;  // 0..60
    for (int k0 = 0; k0 < K; k0 += BK) {
        float4 av = *(const float4*)&A[(size_t)(row0 + arow) * K + k0 + ak];
        float4 bv = *(const float4*)&B[(size_t)(k0 + brow) * N + col0 + bcol];
        As[ak + 0][arow] = av.x;
        As[ak + 1][arow] = av.y;
        As[ak + 2][arow] = av.z;
        As[ak + 3][arow] = av.w;
        *(float4*)&Bs[brow][bcol] = bv;
        __syncthreads();
#pragma unroll
        for (int kk = 0; kk < BK; ++kk) {
            float4 a4 = *(const float4*)&As[kk][ty * 4];
            float4 b4 = *(const float4*)&Bs[kk][tx * 4];
            float avr[4] = {a4.x, a4.y, a4.z, a4.w};
            float bvr[4] = {b4.x, b4.y, b4.z, b4.w};
#pragma unroll
            for (int i = 0; i < 4; ++i)
#pragma unroll
                for (int j = 0; j < 4; ++j)
                    acc[i][j] += avr[i] * bvr[j];
        }
        __syncthreads();
    }
#pragma unroll
    for (int i = 0; i < 4; ++i) {
        int r = row0 + ty * 4 + i;
        float4 o = {acc[i][0], acc[i][1], acc[i][2], acc[i][3]};
        *(float4*)&C[(size_t)r * N + col0 + tx * 4] = o;
    }
}

// In-place softmax over rows of 64 (one wave per row). nrows = B*T*H = 65536.
__global__ __launch_bounds__(256) void softmax64_kernel(float* __restrict__ Q, int nrows) {
    int wave = threadIdx.x >> 6;
    int lane = threadIdx.x & 63;
    int row = blockIdx.x * 4 + wave;
    if (row >= nrows) return;
    float v = Q[(size_t)row * 64 + lane];
    float m = v;
#pragma unroll
    for (int off = 32; off; off >>= 1) m = fmaxf(m, __shfl_xor(m, off));
    float e = __expf(v - m);
    float s = e;
#pragma unroll
    for (int off = 32; off; off >>= 1) s += __shfl_xor(s, off);
    Q[(size_t)row * 64 + lane] = e / s;
}

// One thread per (b,h,l) chain: global max over t, then a = exp(K-M),
// running prefix A, and P = Qs/A. a,P stored as [bh][t][l].
__global__ __launch_bounds__(256) void prep_scan_kernel(const float* __restrict__ Kbuf,
                                                        const float* __restrict__ Qs,
                                                        float* __restrict__ abuf,
                                                        float* __restrict__ Pbuf) {
    int gid = blockIdx.x * 256 + threadIdx.x;  // 0..2047
    int bh = gid >> 6;
    int l = gid & 63;
    int b = bh >> 3, h = bh & 7;
    const float* kp = Kbuf + (size_t)b * 2048 * 512 + h * 64 + l;
    const float* qp = Qs + (size_t)b * 2048 * 512 + h * 64 + l;
    float* ap = abuf + (size_t)bh * 2048 * 64 + l;
    float* pp = Pbuf + (size_t)bh * 2048 * 64 + l;
    float m = -1e30f;
    for (int t = 0; t < 2048; ++t) m = fmaxf(m, kp[(size_t)t * 512]);
    float A = 0.f;
    for (int t = 0; t < 2048; ++t) {
        float a = __expf(kp[(size_t)t * 512] - m);
        A += a;
        ap[(size_t)t * 64] = a;
        pp[(size_t)t * 64] = qp[(size_t)t * 512] / A;
    }
}

// One block per (b,h). 256 threads: d = tid&127, half = tid>>7 owns 32 l's.
// State C[l,d] in registers; y overwrites V in place ([n, D] layout).
__global__ __launch_bounds__(256) void scan_kernel(const float* __restrict__ abuf,
                                                   const float* __restrict__ Pbuf,
                                                   float* __restrict__ Vy) {
    __shared__ float red[128];
    int bh = blockIdx.x;
    int b = bh >> 3, h = bh & 7;
    int d = threadIdx.x & 127;
    int half = threadIdx.x >> 7;
    int l0 = half * 32;
    const float4* ap = (const float4*)(abuf + (size_t)bh * 2048 * 64 + l0);
    const float4* pp = (const float4*)(Pbuf + (size_t)bh * 2048 * 64 + l0);
    float* vp = Vy + (size_t)b * 2048 * 1024 + h * 128 + d;
    float C[32] = {};
    for (int t = 0; t < 2048; ++t) {
        float v = vp[(size_t)t * 1024];
        float yp = 0.f;
#pragma unroll
        for (int i = 0; i < 8; ++i) {
            float4 a4 = ap[t * 16 + i];
            float4 p4 = pp[t * 16 + i];
            C[i * 4 + 0] += a4.x * v;  yp += p4.x * C[i * 4 + 0];
            C[i * 4 + 1] += a4.y * v;  yp += p4.y * C[i * 4 + 1];
            C[i * 4 + 2] += a4.z * v;  yp += p4.z * C[i * 4 + 2];
            C[i * 4 + 3] += a4.w * v;  yp += p4.w * C[i * 4 + 3];
        }
        if (half == 0) red[d] = yp;
        __syncthreads();
        if (half == 1) vp[(size_t)t * 1024] = red[d] + yp;
        __syncthreads();
    }
}

extern "C" void kernel_launch(void* const* d_in, const int* in_sizes, int n_in,
                              void* d_out, int out_size, void* d_ws, size_t ws_size,
                              hipStream_t stream) {
    const float* X  = (const float*)d_in[0];   // [4,2048,1024]
    const float* Wk = (const float*)d_in[1];   // [1024,512]
    const float* Wq = (const float*)d_in[2];   // [1024,512]
    const float* Wv = (const float*)d_in[3];   // [1024,1024]
    const float* Wo = (const float*)d_in[4];   // [1024,1024]
    // d_in[5] = train (ignored, inference path)
    float* ws = (float*)d_ws;
    float* Q  = ws;               // 4,194,304 floats (Qs in place)
    float* Kb = ws + 4194304;     // 4,194,304
    float* Vy = ws + 8388608;     // 8,388,608 (V, then y in place)
    float* ab = ws + 16777216;    // 4,194,304
    float* Pb = ws + 20971520;    // 4,194,304  (total ~96 MB)
    float* out = (float*)d_out;

    dim3 blk(256);
    sgemm_kernel<<<dim3(512 / 64, 8192 / 64), blk, 0, stream>>>(X, Wq, Q, 8192, 512, 1024);
    sgemm_kernel<<<dim3(512 / 64, 8192 / 64), blk, 0, stream>>>(X, Wk, Kb, 8192, 512, 1024);
    sgemm_kernel<<<dim3(1024 / 64, 8192 / 64), blk, 0, stream>>>(X, Wv, Vy, 8192, 1024, 1024);
    softmax64_kernel<<<16384, blk, 0, stream>>>(Q, 65536);
    prep_scan_kernel<<<8, blk, 0, stream>>>(Kb, Q, ab, Pb);
    scan_kernel<<<32, blk, 0, stream>>>(ab, Pb, Vy);
    sgemm_kernel<<<dim3(1024 / 64, 8192 / 64), blk, 0, stream>>>(Vy, Wo, out, 8192, 1024, 1024);
}

// Round 2
// 950.455 us; speedup vs baseline: 3.5317x; 3.5317x over previous
//
#include <hip/hip_runtime.h>
#include <hip/hip_bf16.h>

// Problem constants: B=4, T=2048, D=1024, L=512, H=8, Lh=64, Dh=128
// Chunked linear-scan decomposition: T split into NC=16 chunks of G=128.

#define BM 64
#define BN 64
#define BK 16

// C[M,N] = A[M,K] @ B[K,N], fp32, dims multiples of 64/16.
__global__ __launch_bounds__(256) void sgemm_kernel(const float* __restrict__ A,
                                                    const float* __restrict__ B,
                                                    float* __restrict__ C,
                                                    int M, int N, int K) {
    __shared__ float As[BK][BM];
    __shared__ float Bs[BK][BN];
    int tid = threadIdx.x;
    int tx = tid & 15, ty = tid >> 4;
    int row0 = blockIdx.y * BM;
    int col0 = blockIdx.x * BN;
    float acc[4][4] = {};
    int arow = tid >> 2;
    int ak   = (tid & 3) * 4;
    int brow = tid >> 4;
    int bcol = (tid & 15) * 4;
    for (int k0 = 0; k0 < K; k0 += BK) {
        float4 av = *(const float4*)&A[(size_t)(row0 + arow) * K + k0 + ak];
        float4 bv = *(const float4*)&B[(size_t)(k0 + brow) * N + col0 + bcol];
        As[ak + 0][arow] = av.x;
        As[ak + 1][arow] = av.y;
        As[ak + 2][arow] = av.z;
        As[ak + 3][arow] = av.w;
        *(float4*)&Bs[brow][bcol] = bv;
        __syncthreads();
#pragma unroll
        for (int kk = 0; kk < BK; ++kk) {
            float4 a4 = *(const float4*)&As[kk][ty * 4];
            float4 b4 = *(const float4*)&Bs[kk][tx * 4];
            float avr[4] = {a4.x, a4.y, a4.z, a4.w};
            float bvr[4] = {b4.x, b4.y, b4.z, b4.w};
#pragma unroll
            for (int i = 0; i < 4; ++i)
#pragma unroll
                for (int j = 0; j < 4; ++j)
                    acc[i][j] += avr[i] * bvr[j];
        }
        __syncthreads();
    }
#pragma unroll
    for (int i = 0; i < 4; ++i) {
        int r = row0 + ty * 4 + i;
        float4 o = {acc[i][0], acc[i][1], acc[i][2], acc[i][3]};
        *(float4*)&C[(size_t)r * N + col0 + tx * 4] = o;
    }
}

// In-place softmax over rows of 64 (one wave per row). nrows = B*T*H = 65536.
__global__ __launch_bounds__(256) void softmax64_kernel(float* __restrict__ Q, int nrows) {
    int wave = threadIdx.x >> 6;
    int lane = threadIdx.x & 63;
    int row = blockIdx.x * 4 + wave;
    if (row >= nrows) return;
    float v = Q[(size_t)row * 64 + lane];
    float m = v;
#pragma unroll
    for (int off = 32; off; off >>= 1) m = fmaxf(m, __shfl_xor(m, off));
    float e = __expf(v - m);
    float s = e;
#pragma unroll
    for (int off = 32; off; off >>= 1) s += __shfl_xor(s, off);
    Q[(size_t)row * 64 + lane] = e / s;
}

// Per (bh,c,l): chunk-local max and exp-sum of K. 32768 threads.
__global__ __launch_bounds__(256) void prep_chunkstats_kernel(const float* __restrict__ Kbuf,
                                                              float* __restrict__ mbuf,
                                                              float* __restrict__ sbuf) {
    int gid = blockIdx.x * 256 + threadIdx.x;  // l fastest, then c, then bh
    int l = gid & 63, c = (gid >> 6) & 15, bh = gid >> 10;
    int b = bh >> 3, h = bh & 7;
    const float* kp = Kbuf + (size_t)b * 2048 * 512 + (size_t)(c * 128) * 512 + h * 64 + l;
    float m = -1e30f;
    for (int i = 0; i < 128; ++i) m = fmaxf(m, kp[(size_t)i * 512]);
    float s = 0.f;
    for (int i = 0; i < 128; ++i) s += __expf(kp[(size_t)i * 512] - m);
    mbuf[gid] = m;
    sbuf[gid] = s;
}

// Per (bh,l): combine 16 chunk stats -> global M, exclusive chunk prefix A0.
__global__ __launch_bounds__(256) void prep_combine_kernel(const float* __restrict__ mbuf,
                                                           const float* __restrict__ sbuf,
                                                           float* __restrict__ Mbuf,
                                                           float* __restrict__ A0buf) {
    int gid = blockIdx.x * 256 + threadIdx.x;  // 2048: (bh,l)
    int l = gid & 63, bh = gid >> 6;
    float M = -1e30f;
    for (int c = 0; c < 16; ++c) M = fmaxf(M, mbuf[(bh * 16 + c) * 64 + l]);
    float run = 0.f;
    for (int c = 0; c < 16; ++c) {
        A0buf[(bh * 16 + c) * 64 + l] = run;
        run += sbuf[(bh * 16 + c) * 64 + l] * __expf(mbuf[(bh * 16 + c) * 64 + l] - M);
    }
    Mbuf[gid] = M;
}

// Per (bh,c,l): a = exp(K-M); A = A0 + running sum; P = Qs/A. 32768 threads.
__global__ __launch_bounds__(256) void prep_scan2_kernel(const float* __restrict__ Kbuf,
                                                         const float* __restrict__ Qs,
                                                         const float* __restrict__ Mbuf,
                                                         const float* __restrict__ A0buf,
                                                         float* __restrict__ abuf,
                                                         float* __restrict__ Pbuf) {
    int gid = blockIdx.x * 256 + threadIdx.x;
    int l = gid & 63, c = (gid >> 6) & 15, bh = gid >> 10;
    int b = bh >> 3, h = bh & 7;
    int t0 = c * 128;
    const float* kp = Kbuf + (size_t)b * 2048 * 512 + (size_t)t0 * 512 + h * 64 + l;
    const float* qp = Qs + (size_t)b * 2048 * 512 + (size_t)t0 * 512 + h * 64 + l;
    float* ap = abuf + (size_t)bh * 2048 * 64 + (size_t)t0 * 64 + l;
    float* pp = Pbuf + (size_t)bh * 2048 * 64 + (size_t)t0 * 64 + l;
    float M = Mbuf[bh * 64 + l];
    float A = A0buf[(bh * 16 + c) * 64 + l];
    for (int i = 0; i < 128; ++i) {
        float a = __expf(kp[(size_t)i * 512] - M);
        A += a;
        ap[(size_t)i * 64] = a;
        pp[(size_t)i * 64] = qp[(size_t)i * 512] / A;
    }
}

// Per (bh,c): S_c[l,d] = sum_{t in chunk} a_t[l] * V_t[d]. 512 blocks.
__global__ __launch_bounds__(256) void chunk_sums_kernel(const float* __restrict__ abuf,
                                                         const float* __restrict__ Vy,
                                                         float* __restrict__ Sbuf) {
    __shared__ float la[128 * 64];
    int blk = blockIdx.x;  // bh*16 + c
    int bh = blk >> 4, c = blk & 15;
    int b = bh >> 3, h = bh & 7;
    const float4* ag = (const float4*)(abuf + (size_t)bh * 2048 * 64 + (size_t)c * 128 * 64);
    float4* lag = (float4*)la;
#pragma unroll
    for (int j = 0; j < 8; ++j) lag[threadIdx.x + j * 256] = ag[threadIdx.x + j * 256];
    __syncthreads();
    int d = threadIdx.x >> 1, half = threadIdx.x & 1, l0 = half * 32;
    const float* vp = Vy + (size_t)b * 2048 * 1024 + (size_t)c * 128 * 1024 + h * 128 + d;
    float C[32] = {};
    for (int i = 0; i < 128; ++i) {
        float v = vp[(size_t)i * 1024];
        const float4* arow = (const float4*)(la + i * 64 + l0);
#pragma unroll
        for (int j = 0; j < 8; ++j) {
            float4 a4 = arow[j];
            C[j * 4 + 0] += a4.x * v;
            C[j * 4 + 1] += a4.y * v;
            C[j * 4 + 2] += a4.z * v;
            C[j * 4 + 3] += a4.w * v;
        }
    }
    float* sp = Sbuf + (size_t)blk * 8192 + (size_t)l0 * 128 + d;
#pragma unroll
    for (int j = 0; j < 32; ++j) sp[j * 128] = C[j];
}

// In-place exclusive prefix over the 16 chunks. One thread per (bh,l,d).
__global__ __launch_bounds__(256) void chunk_prefix_kernel(float* __restrict__ Sbuf) {
    int gid = blockIdx.x * 256 + threadIdx.x;  // 262144: d fastest
    int d = gid & 127, l = (gid >> 7) & 63, bh = gid >> 13;
    float run = 0.f;
    for (int c = 0; c < 16; ++c) {
        size_t idx = ((size_t)(bh * 16 + c) * 64 + l) * 128 + d;
        float t = Sbuf[idx];
        Sbuf[idx] = run;
        run += t;
    }
}

// Per (bh,c): init C from exclusive prefix, 128 serial steps, y in place over V.
// Threads: d = tid>>1 (0..127), half = tid&1 owns 32 l's; y-reduce via shfl_xor(1).
__global__ __launch_bounds__(256) void chunk_out_kernel(const float* __restrict__ abuf,
                                                        const float* __restrict__ Pbuf,
                                                        const float* __restrict__ Sbuf,
                                                        float* __restrict__ Vy) {
    __shared__ float la[128 * 64];
    __shared__ float lp[128 * 64];
    int blk = blockIdx.x;
    int bh = blk >> 4, c = blk & 15;
    int b = bh >> 3, h = bh & 7;
    const float4* ag = (const float4*)(abuf + (size_t)bh * 2048 * 64 + (size_t)c * 128 * 64);
    const float4* pg = (const float4*)(Pbuf + (size_t)bh * 2048 * 64 + (size_t)c * 128 * 64);
    float4* lag = (float4*)la;
    float4* lpg = (float4*)lp;
#pragma unroll
    for (int j = 0; j < 8; ++j) {
        lag[threadIdx.x + j * 256] = ag[threadIdx.x + j * 256];
        lpg[threadIdx.x + j * 256] = pg[threadIdx.x + j * 256];
    }
    __syncthreads();
    int d = threadIdx.x >> 1, half = threadIdx.x & 1, l0 = half * 32;
    float* vp = Vy + (size_t)b * 2048 * 1024 + (size_t)c * 128 * 1024 + h * 128 + d;
    const float* sp = Sbuf + (size_t)blk * 8192 + (size_t)l0 * 128 + d;
    float C[32];
#pragma unroll
    for (int j = 0; j < 32; ++j) C[j] = sp[j * 128];
    for (int i = 0; i < 128; ++i) {
        float v = vp[(size_t)i * 1024];
        const float4* arow = (const float4*)(la + i * 64 + l0);
        const float4* prow = (const float4*)(lp + i * 64 + l0);
        float y0 = 0.f, y1 = 0.f, y2 = 0.f, y3 = 0.f;
#pragma unroll
        for (int j = 0; j < 8; ++j) {
            float4 a4 = arow[j];
            float4 p4 = prow[j];
            C[j * 4 + 0] += a4.x * v;  y0 += p4.x * C[j * 4 + 0];
            C[j * 4 + 1] += a4.y * v;  y1 += p4.y * C[j * 4 + 1];
            C[j * 4 + 2] += a4.z * v;  y2 += p4.z * C[j * 4 + 2];
            C[j * 4 + 3] += a4.w * v;  y3 += p4.w * C[j * 4 + 3];
        }
        float yp = (y0 + y1) + (y2 + y3);
        yp += __shfl_xor(yp, 1);  // combine the two l-halves (adjacent lanes, same wave)
        if (half == 0) vp[(size_t)i * 1024] = yp;  // same-wave lockstep: load precedes store
    }
}

extern "C" void kernel_launch(void* const* d_in, const int* in_sizes, int n_in,
                              void* d_out, int out_size, void* d_ws, size_t ws_size,
                              hipStream_t stream) {
    const float* X  = (const float*)d_in[0];   // [4,2048,1024]
    const float* Wk = (const float*)d_in[1];   // [1024,512]
    const float* Wq = (const float*)d_in[2];   // [1024,512]
    const float* Wv = (const float*)d_in[3];   // [1024,1024]
    const float* Wo = (const float*)d_in[4];   // [1024,1024]
    float* ws = (float*)d_ws;
    float* Q  = ws;               // 4,194,304 floats (softmax in place)
    float* Kb = ws + 4194304;     // 4,194,304 — dead after prep_scan2; reused as Sbuf
    float* Vy = ws + 8388608;     // 8,388,608 (V, then y in place)
    float* ab = ws + 16777216;    // 4,194,304
    float* Pb = ws + 20971520;    // 4,194,304  (total 96 MiB)
    float* Sb = Kb;               // 512*64*128 = 4,194,304 floats, exact fit
    float* out = (float*)d_out;
    // Small prep scratch lives in d_out (fully overwritten by the final GEMM).
    float* mbuf = out;            // 32768
    float* sbuf = out + 32768;    // 32768
    float* Mbuf = out + 65536;    // 2048
    float* A0b  = out + 67584;    // 32768

    dim3 blk(256);
    sgemm_kernel<<<dim3(512 / 64, 8192 / 64), blk, 0, stream>>>(X, Wq, Q, 8192, 512, 1024);
    sgemm_kernel<<<dim3(512 / 64, 8192 / 64), blk, 0, stream>>>(X, Wk, Kb, 8192, 512, 1024);
    sgemm_kernel<<<dim3(1024 / 64, 8192 / 64), blk, 0, stream>>>(X, Wv, Vy, 8192, 1024, 1024);
    softmax64_kernel<<<16384, blk, 0, stream>>>(Q, 65536);
    prep_chunkstats_kernel<<<128, blk, 0, stream>>>(Kb, mbuf, sbuf);
    prep_combine_kernel<<<8, blk, 0, stream>>>(mbuf, sbuf, Mbuf, A0b);
    prep_scan2_kernel<<<128, blk, 0, stream>>>(Kb, Q, Mbuf, A0b, ab, Pb);
    chunk_sums_kernel<<<512, blk, 0, stream>>>(ab, Vy, Sb);
    chunk_prefix_kernel<<<1024, blk, 0, stream>>>(Sb);
    chunk_out_kernel<<<512, blk, 0, stream>>>(ab, Pb, Sb, Vy);
    sgemm_kernel<<<dim3(1024 / 64, 8192 / 64), blk, 0, stream>>>(Vy, Wo, out, 8192, 1024, 1024);
}

// Round 3
// 390.157 us; speedup vs baseline: 8.6035x; 2.4361x over previous
//
#include <hip/hip_runtime.h>
#include <hip/hip_bf16.h>

// B=4, T=2048, D=1024, L=512, H=8, Lh=64, Dh=128. Chunks: NC=16 of G=128.
// Pipeline: cast/transpose -> bf16 MFMA GEMMs (Q,K,V) -> softmax -> chunked
// stable linear scan (a/P/V bf16 in HBM, fp32 in LDS/registers) -> bf16 y ->
// MFMA output GEMM.

typedef __attribute__((ext_vector_type(8))) short bf16x8;
typedef __attribute__((ext_vector_type(4))) float f32x4;

__device__ inline ushort f2bf(float f) {
    unsigned u = __float_as_uint(f);
    unsigned r = (u + 0x7fff + ((u >> 16) & 1)) >> 16;
    return (ushort)r;
}
__device__ inline float bf2f(ushort h) { return __uint_as_float(((unsigned)h) << 16); }
__device__ inline float bflo(unsigned x) { return __uint_as_float(x << 16); }
__device__ inline float bfhi(unsigned x) { return __uint_as_float(x & 0xffff0000u); }

__device__ inline void gload_lds16(const ushort* g, ushort* l) {
    __builtin_amdgcn_global_load_lds((const __attribute__((address_space(1))) void*)g,
                                     (__attribute__((address_space(3))) void*)l, 16, 0, 0);
}

// X fp32 -> bf16, 4 elems/thread.
__global__ __launch_bounds__(256) void cast_x_kernel(const float* __restrict__ X,
                                                     ushort* __restrict__ Xb) {
    int i = blockIdx.x * 1024 + threadIdx.x * 4;
    float4 v = *(const float4*)(X + i);
    ushort4 o = {f2bf(v.x), f2bf(v.y), f2bf(v.z), f2bf(v.w)};
    *(ushort4*)(Xb + i) = o;
}

// W [K,N] fp32 -> WT [N,K] bf16 (32x32 LDS tiles).
__global__ __launch_bounds__(256) void transpose_cast_kernel(const float* __restrict__ W,
                                                             ushort* __restrict__ WT,
                                                             int K, int N) {
    __shared__ float s[32][33];
    int n0 = blockIdx.x * 32, k0 = blockIdx.y * 32;
    int tx = threadIdx.x & 31, ty0 = threadIdx.x >> 5;
#pragma unroll
    for (int r = 0; r < 4; ++r) {
        int row = ty0 + r * 8;
        s[row][tx] = W[(size_t)(k0 + row) * N + n0 + tx];
    }
    __syncthreads();
#pragma unroll
    for (int r = 0; r < 4; ++r) {
        int row = ty0 + r * 8;
        WT[(size_t)(n0 + row) * K + k0 + tx] = f2bf(s[tx][row]);
    }
}

// C[M,N] = A[M,K] @ B[K,N]; A bf16 row-major, BT = B^T bf16 [N,K] row-major.
// 128x128 block tile, BK=32, 4 waves, 4x4 16x16 frags/wave, global_load_lds.
template <int WRITE_BF16>
__global__ __launch_bounds__(256) void mfma_gemm(const ushort* __restrict__ A,
                                                 const ushort* __restrict__ BT,
                                                 float* __restrict__ Cf,
                                                 ushort* __restrict__ Cb,
                                                 int M, int N, int K) {
    __shared__ __align__(16) ushort As[128 * 32];
    __shared__ __align__(16) ushort Bs[128 * 32];
    const int tid = threadIdx.x;
    const int w = tid >> 6, lane = tid & 63;
    const int quad = lane >> 4, l15 = lane & 15;
    const int m0 = blockIdx.y * 128, n0 = blockIdx.x * 128;
    const int wm = (w & 1) * 64, wn = (w >> 1) * 64;
    f32x4 acc[4][4] = {};
    // staging: 16B chunk c = j*256+tid covers row c>>2, k-cols (c&3)*8..+8
    const int r0 = tid >> 2, kc = (tid & 3) * 8;
    const int r1 = 64 + r0;
    const ushort* Arow0 = A + (size_t)(m0 + r0) * K + kc;
    const ushort* Arow1 = A + (size_t)(m0 + r1) * K + kc;
    const ushort* Brow0 = BT + (size_t)(n0 + r0) * K + kc;
    const ushort* Brow1 = BT + (size_t)(n0 + r1) * K + kc;
    ushort* AsW0 = As + (w * 64) * 8;          // wave-uniform LDS dests
    ushort* AsW1 = As + (256 + w * 64) * 8;
    ushort* BsW0 = Bs + (w * 64) * 8;
    ushort* BsW1 = Bs + (256 + w * 64) * 8;
    const ushort* afp = As + (wm + l15) * 32 + quad * 8;
    const ushort* bfp = Bs + (wn + l15) * 32 + quad * 8;
    for (int k0 = 0; k0 < K; k0 += 32) {
        gload_lds16(Arow0 + k0, AsW0);
        gload_lds16(Arow1 + k0, AsW1);
        gload_lds16(Brow0 + k0, BsW0);
        gload_lds16(Brow1 + k0, BsW1);
        __syncthreads();
        bf16x8 af[4], bf[4];
#pragma unroll
        for (int i = 0; i < 4; ++i) {
            af[i] = *(const bf16x8*)(afp + i * 16 * 32);
            bf[i] = *(const bf16x8*)(bfp + i * 16 * 32);
        }
#pragma unroll
        for (int i = 0; i < 4; ++i)
#pragma unroll
            for (int j = 0; j < 4; ++j)
                acc[i][j] = __builtin_amdgcn_mfma_f32_16x16x32_bf16(af[i], bf[j], acc[i][j], 0, 0, 0);
        __syncthreads();
    }
    const int crow = m0 + wm + quad * 4;
    const int ccol = n0 + wn + l15;
#pragma unroll
    for (int i = 0; i < 4; ++i)
#pragma unroll
        for (int j = 0; j < 4; ++j) {
            f32x4 v = acc[i][j];
#pragma unroll
            for (int r = 0; r < 4; ++r) {
                size_t idx = (size_t)(crow + i * 16 + r) * N + ccol + j * 16;
                if (WRITE_BF16) Cb[idx] = f2bf(v[r]);
                else Cf[idx] = v[r];
            }
        }
}

// In-place softmax over rows of 64 (one wave per row). nrows = B*T*H = 65536.
__global__ __launch_bounds__(256) void softmax64_kernel(float* __restrict__ Q, int nrows) {
    int wave = threadIdx.x >> 6;
    int lane = threadIdx.x & 63;
    int row = blockIdx.x * 4 + wave;
    if (row >= nrows) return;
    float v = Q[(size_t)row * 64 + lane];
    float m = v;
#pragma unroll
    for (int off = 32; off; off >>= 1) m = fmaxf(m, __shfl_xor(m, off));
    float e = __expf(v - m);
    float s = e;
#pragma unroll
    for (int off = 32; off; off >>= 1) s += __shfl_xor(s, off);
    Q[(size_t)row * 64 + lane] = e / s;
}

// Per (bh,c,l): chunk-local max and exp-sum of K. 32768 threads.
__global__ __launch_bounds__(256) void prep_chunkstats_kernel(const float* __restrict__ Kbuf,
                                                              float* __restrict__ mbuf,
                                                              float* __restrict__ sbuf) {
    int gid = blockIdx.x * 256 + threadIdx.x;
    int l = gid & 63, c = (gid >> 6) & 15, bh = gid >> 10;
    int b = bh >> 3, h = bh & 7;
    const float* kp = Kbuf + (size_t)b * 2048 * 512 + (size_t)(c * 128) * 512 + h * 64 + l;
    float m = -1e30f;
    for (int i = 0; i < 128; ++i) m = fmaxf(m, kp[(size_t)i * 512]);
    float s = 0.f;
    for (int i = 0; i < 128; ++i) s += __expf(kp[(size_t)i * 512] - m);
    mbuf[gid] = m;
    sbuf[gid] = s;
}

// Per (bh,l): combine 16 chunk stats -> global M, exclusive chunk prefix A0.
__global__ __launch_bounds__(256) void prep_combine_kernel(const float* __restrict__ mbuf,
                                                           const float* __restrict__ sbuf,
                                                           float* __restrict__ Mbuf,
                                                           float* __restrict__ A0buf) {
    int gid = blockIdx.x * 256 + threadIdx.x;  // 2048
    int l = gid & 63, bh = gid >> 6;
    float M = -1e30f;
    for (int c = 0; c < 16; ++c) M = fmaxf(M, mbuf[(bh * 16 + c) * 64 + l]);
    float run = 0.f;
    for (int c = 0; c < 16; ++c) {
        A0buf[(bh * 16 + c) * 64 + l] = run;
        run += sbuf[(bh * 16 + c) * 64 + l] * __expf(mbuf[(bh * 16 + c) * 64 + l] - M);
    }
    Mbuf[gid] = M;
}

// Per (bh,c,l): a = exp(K-M); A = A0 + running; P = Qs/A. bf16 outputs.
__global__ __launch_bounds__(256) void prep_scan2_kernel(const float* __restrict__ Kbuf,
                                                         const float* __restrict__ Qs,
                                                         const float* __restrict__ Mbuf,
                                                         const float* __restrict__ A0buf,
                                                         ushort* __restrict__ abuf,
                                                         ushort* __restrict__ Pbuf) {
    int gid = blockIdx.x * 256 + threadIdx.x;
    int l = gid & 63, c = (gid >> 6) & 15, bh = gid >> 10;
    int b = bh >> 3, h = bh & 7;
    int t0 = c * 128;
    const float* kp = Kbuf + (size_t)b * 2048 * 512 + (size_t)t0 * 512 + h * 64 + l;
    const float* qp = Qs + (size_t)b * 2048 * 512 + (size_t)t0 * 512 + h * 64 + l;
    ushort* ap = abuf + (size_t)bh * 2048 * 64 + (size_t)t0 * 64 + l;
    ushort* pp = Pbuf + (size_t)bh * 2048 * 64 + (size_t)t0 * 64 + l;
    float M = Mbuf[bh * 64 + l];
    float A = A0buf[(bh * 16 + c) * 64 + l];
    for (int i = 0; i < 128; ++i) {
        float a = __expf(kp[(size_t)i * 512] - M);
        A += a;
        ap[(size_t)i * 64] = f2bf(a);
        pp[(size_t)i * 64] = f2bf(qp[(size_t)i * 512] / A);
    }
}

// Per (bh,c): S_c[l,d] = sum_t a_t[l]*V_t[d]. a,V bf16 in; S fp32 out.
__global__ __launch_bounds__(256) void chunk_sums_kernel(const ushort* __restrict__ abuf,
                                                         const ushort* __restrict__ Vy,
                                                         float* __restrict__ Sbuf) {
    __shared__ __align__(16) float la[128 * 64];
    int blk = blockIdx.x, bh = blk >> 4, c = blk & 15;
    int b = bh >> 3, h = bh & 7;
    const uint4* ag = (const uint4*)(abuf + (size_t)(bh * 2048 + c * 128) * 64);
#pragma unroll
    for (int j = 0; j < 4; ++j) {
        int idx = threadIdx.x + j * 256;
        uint4 u = ag[idx];
        float* lp = la + idx * 8;
        lp[0] = bflo(u.x); lp[1] = bfhi(u.x);
        lp[2] = bflo(u.y); lp[3] = bfhi(u.y);
        lp[4] = bflo(u.z); lp[5] = bfhi(u.z);
        lp[6] = bflo(u.w); lp[7] = bfhi(u.w);
    }
    __syncthreads();
    int d = threadIdx.x >> 1, half = threadIdx.x & 1, l0 = half * 32;
    const ushort* vp = Vy + (size_t)(b * 2048 + c * 128) * 1024 + h * 128 + d;
    float C[32] = {};
    for (int i = 0; i < 128; ++i) {
        float v = bf2f(vp[(size_t)i * 1024]);
        const float4* arow = (const float4*)(la + i * 64 + l0);
#pragma unroll
        for (int j = 0; j < 8; ++j) {
            float4 a4 = arow[j];
            C[j * 4 + 0] += a4.x * v;
            C[j * 4 + 1] += a4.y * v;
            C[j * 4 + 2] += a4.z * v;
            C[j * 4 + 3] += a4.w * v;
        }
    }
    float* sp = Sbuf + (size_t)blk * 8192 + (size_t)l0 * 128 + d;
#pragma unroll
    for (int j = 0; j < 32; ++j) sp[j * 128] = C[j];
}

// In-place exclusive prefix over the 16 chunks. One thread per (bh,l,d).
__global__ __launch_bounds__(256) void chunk_prefix_kernel(float* __restrict__ Sbuf) {
    int gid = blockIdx.x * 256 + threadIdx.x;  // 262144
    int d = gid & 127, l = (gid >> 7) & 63, bh = gid >> 13;
    float run = 0.f;
    for (int c = 0; c < 16; ++c) {
        size_t idx = ((size_t)(bh * 16 + c) * 64 + l) * 128 + d;
        float t = Sbuf[idx];
        Sbuf[idx] = run;
        run += t;
    }
}

// Per (bh,c): init C from prefix, 128 serial steps, write y bf16 to Yb.
__global__ __launch_bounds__(256) void chunk_out_kernel(const ushort* __restrict__ abuf,
                                                        const ushort* __restrict__ Pbuf,
                                                        const float* __restrict__ Sbuf,
                                                        const ushort* __restrict__ Vy,
                                                        ushort* __restrict__ Yb) {
    __shared__ __align__(16) float la[128 * 64];
    __shared__ __align__(16) float lp[128 * 64];
    int blk = blockIdx.x, bh = blk >> 4, c = blk & 15;
    int b = bh >> 3, h = bh & 7;
    const uint4* ag = (const uint4*)(abuf + (size_t)(bh * 2048 + c * 128) * 64);
    const uint4* pg = (const uint4*)(Pbuf + (size_t)(bh * 2048 + c * 128) * 64);
#pragma unroll
    for (int j = 0; j < 4; ++j) {
        int idx = threadIdx.x + j * 256;
        uint4 u = ag[idx];
        float* w0 = la + idx * 8;
        w0[0] = bflo(u.x); w0[1] = bfhi(u.x);
        w0[2] = bflo(u.y); w0[3] = bfhi(u.y);
        w0[4] = bflo(u.z); w0[5] = bfhi(u.z);
        w0[6] = bflo(u.w); w0[7] = bfhi(u.w);
        uint4 q = pg[idx];
        float* w1 = lp + idx * 8;
        w1[0] = bflo(q.x); w1[1] = bfhi(q.x);
        w1[2] = bflo(q.y); w1[3] = bfhi(q.y);
        w1[4] = bflo(q.z); w1[5] = bfhi(q.z);
        w1[6] = bflo(q.w); w1[7] = bfhi(q.w);
    }
    __syncthreads();
    int d = threadIdx.x >> 1, half = threadIdx.x & 1, l0 = half * 32;
    const ushort* vp = Vy + (size_t)(b * 2048 + c * 128) * 1024 + h * 128 + d;
    ushort* yp = Yb + (size_t)(b * 2048 + c * 128) * 1024 + h * 128 + d;
    const float* sp = Sbuf + (size_t)blk * 8192 + (size_t)l0 * 128 + d;
    float C[32];
#pragma unroll
    for (int j = 0; j < 32; ++j) C[j] = sp[j * 128];
    for (int i = 0; i < 128; ++i) {
        float v = bf2f(vp[(size_t)i * 1024]);
        const float4* arow = (const float4*)(la + i * 64 + l0);
        const float4* prow = (const float4*)(lp + i * 64 + l0);
        float y0 = 0.f, y1 = 0.f, y2 = 0.f, y3 = 0.f;
#pragma unroll
        for (int j = 0; j < 8; ++j) {
            float4 a4 = arow[j];
            float4 p4 = prow[j];
            C[j * 4 + 0] += a4.x * v;  y0 += p4.x * C[j * 4 + 0];
            C[j * 4 + 1] += a4.y * v;  y1 += p4.y * C[j * 4 + 1];
            C[j * 4 + 2] += a4.z * v;  y2 += p4.z * C[j * 4 + 2];
            C[j * 4 + 3] += a4.w * v;  y3 += p4.w * C[j * 4 + 3];
        }
        float ysum = (y0 + y1) + (y2 + y3);
        ysum += __shfl_xor(ysum, 1);  // combine the two l-halves
        if (half == 0) yp[(size_t)i * 1024] = f2bf(ysum);
    }
}

extern "C" void kernel_launch(void* const* d_in, const int* in_sizes, int n_in,
                              void* d_out, int out_size, void* d_ws, size_t ws_size,
                              hipStream_t stream) {
    const float* X  = (const float*)d_in[0];   // [4,2048,1024]
    const float* Wk = (const float*)d_in[1];   // [1024,512]
    const float* Wq = (const float*)d_in[2];   // [1024,512]
    const float* Wv = (const float*)d_in[3];   // [1024,1024]
    const float* Wo = (const float*)d_in[4];   // [1024,1024]
    float* ws = (float*)d_ws;
    // Layout (float units; total 22.6M fu = 86 MB <= 96 MiB proven budget):
    ushort* Xb  = (ushort*)ws;                  // bf16 X [8192,1024]; reused as Yb
    float*  Q   = ws + 4194304;                 // fp32 Qs [8192,512]
    float*  Kb  = ws + 8388608;                 // fp32 K  [8192,512]; reused as Sb
    ushort* Vy  = (ushort*)(ws + 12582912);     // bf16 V [8192,1024]
    ushort* ab  = (ushort*)(ws + 16777216);     // bf16 a [32][2048][64]
    ushort* Pb  = (ushort*)(ws + 18874368);     // bf16 P [32][2048][64]
    ushort* WqT = (ushort*)(ws + 20971520);     // bf16 [512,1024]
    ushort* WkT = (ushort*)(ws + 21233664);     // bf16 [512,1024]
    ushort* WvT = (ushort*)(ws + 21495808);     // bf16 [1024,1024]
    ushort* WoT = (ushort*)(ws + 22020096);     // bf16 [1024,1024]
    float* Sb = Kb;
    ushort* Yb = Xb;
    float* out = (float*)d_out;
    // Small prep scratch in d_out (fully overwritten by the final GEMM).
    float* mbuf = out;            // 32768
    float* sbuf = out + 32768;    // 32768
    float* Mbuf = out + 65536;    // 2048
    float* A0b  = out + 67584;    // 32768

    dim3 blk(256);
    cast_x_kernel<<<8192, blk, 0, stream>>>(X, Xb);
    transpose_cast_kernel<<<dim3(16, 32), blk, 0, stream>>>(Wq, WqT, 1024, 512);
    transpose_cast_kernel<<<dim3(16, 32), blk, 0, stream>>>(Wk, WkT, 1024, 512);
    transpose_cast_kernel<<<dim3(32, 32), blk, 0, stream>>>(Wv, WvT, 1024, 1024);
    transpose_cast_kernel<<<dim3(32, 32), blk, 0, stream>>>(Wo, WoT, 1024, 1024);
    mfma_gemm<0><<<dim3(4, 64), blk, 0, stream>>>(Xb, WqT, Q, nullptr, 8192, 512, 1024);
    mfma_gemm<0><<<dim3(4, 64), blk, 0, stream>>>(Xb, WkT, Kb, nullptr, 8192, 512, 1024);
    mfma_gemm<1><<<dim3(8, 64), blk, 0, stream>>>(Xb, WvT, nullptr, Vy, 8192, 1024, 1024);
    softmax64_kernel<<<16384, blk, 0, stream>>>(Q, 65536);
    prep_chunkstats_kernel<<<128, blk, 0, stream>>>(Kb, mbuf, sbuf);
    prep_combine_kernel<<<8, blk, 0, stream>>>(mbuf, sbuf, Mbuf, A0b);
    prep_scan2_kernel<<<128, blk, 0, stream>>>(Kb, Q, Mbuf, A0b, ab, Pb);
    chunk_sums_kernel<<<512, blk, 0, stream>>>(ab, Vy, Sb);
    chunk_prefix_kernel<<<1024, blk, 0, stream>>>(Sb);
    chunk_out_kernel<<<512, blk, 0, stream>>>(ab, Pb, Sb, Vy, Yb);
    mfma_gemm<0><<<dim3(8, 64), blk, 0, stream>>>(Yb, WoT, out, nullptr, 8192, 1024, 1024);
}

// Round 5
// 360.152 us; speedup vs baseline: 9.3202x; 1.0833x over previous
//
#include <hip/hip_runtime.h>
#include <hip/hip_bf16.h>

// B=4, T=2048, D=1024, L=512, H=8, Lh=64, Dh=128. Chunks: NC=16 of G=128.
// Chunked linear scan as MFMA matmuls:
//   S_c^T[d,l] = sum_t V[t,d] a_t[l]            (chunk_sums_mfma)
//   C0 = exclusive prefix of S over chunks       (chunk_prefix)
//   G^T = A @ P^T, mask s<=i, Y = Gm@V + P@C0    (chunk_out_mfma)

typedef __attribute__((ext_vector_type(8))) short bf16x8;
typedef __attribute__((ext_vector_type(4))) float f32x4;

__device__ inline ushort f2bf(float f) {
    unsigned u = __float_as_uint(f);
    unsigned r = (u + 0x7fff + ((u >> 16) & 1)) >> 16;
    return (ushort)r;
}
__device__ inline float bf2f(ushort h) { return __uint_as_float(((unsigned)h) << 16); }

__device__ inline void gload_lds16(const ushort* g, ushort* l) {
    __builtin_amdgcn_global_load_lds((const __attribute__((address_space(1))) void*)g,
                                     (__attribute__((address_space(3))) void*)l, 16, 0, 0);
}

// X fp32 -> bf16, 4 elems/thread.
__global__ __launch_bounds__(256) void cast_x_kernel(const float* __restrict__ X,
                                                     ushort* __restrict__ Xb) {
    int i = blockIdx.x * 1024 + threadIdx.x * 4;
    float4 v = *(const float4*)(X + i);
    ushort4 o = {f2bf(v.x), f2bf(v.y), f2bf(v.z), f2bf(v.w)};
    *(ushort4*)(Xb + i) = o;
}

// W [K,N] fp32 -> WT [N,K] bf16 (32x32 LDS tiles).
__global__ __launch_bounds__(256) void transpose_cast_kernel(const float* __restrict__ W,
                                                             ushort* __restrict__ WT,
                                                             int K, int N) {
    __shared__ float s[32][33];
    int n0 = blockIdx.x * 32, k0 = blockIdx.y * 32;
    int tx = threadIdx.x & 31, ty0 = threadIdx.x >> 5;
#pragma unroll
    for (int r = 0; r < 4; ++r) {
        int row = ty0 + r * 8;
        s[row][tx] = W[(size_t)(k0 + row) * N + n0 + tx];
    }
    __syncthreads();
#pragma unroll
    for (int r = 0; r < 4; ++r) {
        int row = ty0 + r * 8;
        WT[(size_t)(n0 + row) * K + k0 + tx] = f2bf(s[tx][row]);
    }
}

// C[M,N] = A[M,K] @ B[K,N]; A bf16 row-major, BT = B^T bf16 [N,K] row-major.
// MODE 0: write fp32 C natural. MODE 2: write bf16 VT[bh][d][t] (V GEMM, N=1024).
template <int MODE>
__global__ __launch_bounds__(256) void mfma_gemm(const ushort* __restrict__ A,
                                                 const ushort* __restrict__ BT,
                                                 float* __restrict__ Cf,
                                                 ushort* __restrict__ Cb,
                                                 int M, int N, int K) {
    __shared__ __align__(16) ushort As[128 * 32];
    __shared__ __align__(16) ushort Bs[128 * 32];
    const int tid = threadIdx.x;
    const int w = tid >> 6, lane = tid & 63;
    const int quad = lane >> 4, l15 = lane & 15;
    const int m0 = blockIdx.y * 128, n0 = blockIdx.x * 128;
    const int wm = (w & 1) * 64, wn = (w >> 1) * 64;
    f32x4 acc[4][4] = {};
    const int r0 = tid >> 2, kc = (tid & 3) * 8;
    const int r1 = 64 + r0;
    const ushort* Arow0 = A + (size_t)(m0 + r0) * K + kc;
    const ushort* Arow1 = A + (size_t)(m0 + r1) * K + kc;
    const ushort* Brow0 = BT + (size_t)(n0 + r0) * K + kc;
    const ushort* Brow1 = BT + (size_t)(n0 + r1) * K + kc;
    ushort* AsW0 = As + (w * 64) * 8;
    ushort* AsW1 = As + (256 + w * 64) * 8;
    ushort* BsW0 = Bs + (w * 64) * 8;
    ushort* BsW1 = Bs + (256 + w * 64) * 8;
    const ushort* afp = As + (wm + l15) * 32 + quad * 8;
    const ushort* bfp = Bs + (wn + l15) * 32 + quad * 8;
    for (int k0 = 0; k0 < K; k0 += 32) {
        gload_lds16(Arow0 + k0, AsW0);
        gload_lds16(Arow1 + k0, AsW1);
        gload_lds16(Brow0 + k0, BsW0);
        gload_lds16(Brow1 + k0, BsW1);
        __syncthreads();
        bf16x8 af[4], bf[4];
#pragma unroll
        for (int i = 0; i < 4; ++i) {
            af[i] = *(const bf16x8*)(afp + i * 16 * 32);
            bf[i] = *(const bf16x8*)(bfp + i * 16 * 32);
        }
#pragma unroll
        for (int i = 0; i < 4; ++i)
#pragma unroll
            for (int j = 0; j < 4; ++j)
                acc[i][j] = __builtin_amdgcn_mfma_f32_16x16x32_bf16(af[i], bf[j], acc[i][j], 0, 0, 0);
        __syncthreads();
    }
    const int crow = m0 + wm + quad * 4;
    const int ccol = n0 + wn + l15;
#pragma unroll
    for (int i = 0; i < 4; ++i)
#pragma unroll
        for (int j = 0; j < 4; ++j) {
            f32x4 v = acc[i][j];
            if (MODE == 2) {
                int col = ccol + j * 16;
                int h = col >> 7, dd = col & 127;
                int row = crow + i * 16;
                int bb = row >> 11, t = row & 2047;
                ushort4 o = {f2bf(v[0]), f2bf(v[1]), f2bf(v[2]), f2bf(v[3])};
                *(ushort4*)(Cb + ((size_t)(bb * 8 + h) * 128 + dd) * 2048 + t) = o;
            } else {
#pragma unroll
                for (int r = 0; r < 4; ++r)
                    Cf[(size_t)(crow + i * 16 + r) * N + ccol + j * 16] = v[r];
            }
        }
}

// In-place softmax over rows of 64 (one wave per row). nrows = 65536.
__global__ __launch_bounds__(256) void softmax64_kernel(float* __restrict__ Q, int nrows) {
    int wave = threadIdx.x >> 6;
    int lane = threadIdx.x & 63;
    int row = blockIdx.x * 4 + wave;
    if (row >= nrows) return;
    float v = Q[(size_t)row * 64 + lane];
    float m = v;
#pragma unroll
    for (int off = 32; off; off >>= 1) m = fmaxf(m, __shfl_xor(m, off));
    float e = __expf(v - m);
    float s = e;
#pragma unroll
    for (int off = 32; off; off >>= 1) s += __shfl_xor(s, off);
    Q[(size_t)row * 64 + lane] = e / s;
}

// Per (bh,c,l): chunk-local max and exp-sum of K. 32768 threads.
__global__ __launch_bounds__(256) void prep_chunkstats_kernel(const float* __restrict__ Kbuf,
                                                              float* __restrict__ mbuf,
                                                              float* __restrict__ sbuf) {
    int gid = blockIdx.x * 256 + threadIdx.x;
    int l = gid & 63, c = (gid >> 6) & 15, bh = gid >> 10;
    int b = bh >> 3, h = bh & 7;
    const float* kp = Kbuf + (size_t)b * 2048 * 512 + (size_t)(c * 128) * 512 + h * 64 + l;
    float m = -1e30f;
    for (int i = 0; i < 128; ++i) m = fmaxf(m, kp[(size_t)i * 512]);
    float s = 0.f;
    for (int i = 0; i < 128; ++i) s += __expf(kp[(size_t)i * 512] - m);
    mbuf[gid] = m;
    sbuf[gid] = s;
}

// Per (bh,l): combine 16 chunk stats -> global M, exclusive chunk prefix A0.
__global__ __launch_bounds__(256) void prep_combine_kernel(const float* __restrict__ mbuf,
                                                           const float* __restrict__ sbuf,
                                                           float* __restrict__ Mbuf,
                                                           float* __restrict__ A0buf) {
    int gid = blockIdx.x * 256 + threadIdx.x;  // 2048
    int l = gid & 63, bh = gid >> 6;
    float M = -1e30f;
    for (int c = 0; c < 16; ++c) M = fmaxf(M, mbuf[(bh * 16 + c) * 64 + l]);
    float run = 0.f;
    for (int c = 0; c < 16; ++c) {
        A0buf[(bh * 16 + c) * 64 + l] = run;
        run += sbuf[(bh * 16 + c) * 64 + l] * __expf(mbuf[(bh * 16 + c) * 64 + l] - M);
    }
    Mbuf[gid] = M;
}

// Per (bh,c,l): a = exp(K-M); A = A0 + running; P = Qs/A.
// Writes a natural [bh][t][l], aT [bh][l][t], P natural.
__global__ __launch_bounds__(256) void prep_scan2_kernel(const float* __restrict__ Kbuf,
                                                         const float* __restrict__ Qs,
                                                         const float* __restrict__ Mbuf,
                                                         const float* __restrict__ A0buf,
                                                         ushort* __restrict__ abuf,
                                                         ushort* __restrict__ aTbuf,
                                                         ushort* __restrict__ Pbuf) {
    int gid = blockIdx.x * 256 + threadIdx.x;
    int l = gid & 63, c = (gid >> 6) & 15, bh = gid >> 10;
    int b = bh >> 3, h = bh & 7;
    int t0 = c * 128;
    const float* kp = Kbuf + (size_t)b * 2048 * 512 + (size_t)t0 * 512 + h * 64 + l;
    const float* qp = Qs + (size_t)b * 2048 * 512 + (size_t)t0 * 512 + h * 64 + l;
    ushort* ap = abuf + (size_t)bh * 2048 * 64 + (size_t)t0 * 64 + l;
    ushort* atp = aTbuf + ((size_t)bh * 64 + l) * 2048 + t0;
    ushort* pp = Pbuf + (size_t)bh * 2048 * 64 + (size_t)t0 * 64 + l;
    float M = Mbuf[bh * 64 + l];
    float A = A0buf[(bh * 16 + c) * 64 + l];
    ushort tmp[8];
    for (int i = 0; i < 128; ++i) {
        float a = __expf(kp[(size_t)i * 512] - M);
        A += a;
        ushort abf = f2bf(a);
        ap[(size_t)i * 64] = abf;
        tmp[i & 7] = abf;
        if ((i & 7) == 7) *(uint4*)(atp + i - 7) = *(uint4*)tmp;
        pp[(size_t)i * 64] = f2bf(qp[(size_t)i * 512] / A);
    }
}

// Per (bh,c): S^T[d,l] = sum_t V[t,d] a_t[l] via MFMA. S layout [blk][d=128][l=64] fp32.
__global__ __launch_bounds__(256) void chunk_sums_mfma(const ushort* __restrict__ aT,
                                                       const ushort* __restrict__ VT,
                                                       float* __restrict__ S) {
    int blk = blockIdx.x, bh = blk >> 4, c = blk & 15;
    int w = threadIdx.x >> 6, lane = threadIdx.x & 63;
    int quad = lane >> 4, l15 = lane & 15;
    const ushort* vtb = VT + (size_t)bh * 128 * 2048 + c * 128;
    const ushort* atb = aT + (size_t)bh * 64 * 2048 + c * 128;
    f32x4 acc[2][4] = {};
#pragma unroll
    for (int ks = 0; ks < 4; ++ks) {
        bf16x8 af[2];
#pragma unroll
        for (int mi = 0; mi < 2; ++mi)
            af[mi] = *(const bf16x8*)(vtb + (size_t)(w * 32 + mi * 16 + l15) * 2048 + ks * 32 + quad * 8);
#pragma unroll
        for (int nj = 0; nj < 4; ++nj) {
            bf16x8 bfr = *(const bf16x8*)(atb + (size_t)(nj * 16 + l15) * 2048 + ks * 32 + quad * 8);
#pragma unroll
            for (int mi = 0; mi < 2; ++mi)
                acc[mi][nj] = __builtin_amdgcn_mfma_f32_16x16x32_bf16(af[mi], bfr, acc[mi][nj], 0, 0, 0);
        }
    }
    float* sp = S + (size_t)blk * 8192;
#pragma unroll
    for (int mi = 0; mi < 2; ++mi)
#pragma unroll
        for (int nj = 0; nj < 4; ++nj) {
            f32x4 v = acc[mi][nj];
#pragma unroll
            for (int r = 0; r < 4; ++r)
                sp[(w * 32 + mi * 16 + quad * 4 + r) * 64 + nj * 16 + l15] = v[r];
        }
}

// In-place exclusive prefix over the 16 chunks; S layout [bh][c][d][l].
__global__ __launch_bounds__(256) void chunk_prefix_kernel(float* __restrict__ Sbuf) {
    int gid = blockIdx.x * 256 + threadIdx.x;  // 262144
    int l = gid & 63, d = (gid >> 6) & 127, bh = gid >> 13;
    float run = 0.f;
    for (int c = 0; c < 16; ++c) {
        size_t idx = (size_t)(bh * 16 + c) * 8192 + d * 64 + l;
        float t = Sbuf[idx];
        Sbuf[idx] = run;
        run += t;
    }
}

// Per (bh,c): G^T = A @ P^T (C-layout row=s,col=i), mask s<=i, pack to LDS bf16;
// Y = Gm @ V (K=128, b-frag from VT) + P @ C0 (K=64, b-frag from S fp32).
__global__ __launch_bounds__(256) void chunk_out_mfma(const ushort* __restrict__ ab,
                                                      const ushort* __restrict__ Pb,
                                                      const ushort* __restrict__ VT,
                                                      const float* __restrict__ S,
                                                      ushort* __restrict__ Yb) {
    __shared__ __align__(16) ushort Gs[128 * 136];  // [i][s], +8 pad kills conflicts
    int blk = blockIdx.x, bh = blk >> 4, c = blk & 15;
    int b = bh >> 3, h = bh & 7;
    int w = threadIdx.x >> 6, lane = threadIdx.x & 63;
    int quad = lane >> 4, l15 = lane & 15;
    const ushort* Pc = Pb + (size_t)(bh * 2048 + c * 128) * 64;
    const ushort* Ac = ab + (size_t)(bh * 2048 + c * 128) * 64;
    // Phase 1: G^T = A @ P^T for cols i in [w*32, w*32+32)
    f32x4 g[8][2] = {};
#pragma unroll
    for (int ks = 0; ks < 2; ++ks) {
        bf16x8 bfr[2];
#pragma unroll
        for (int ni = 0; ni < 2; ++ni)
            bfr[ni] = *(const bf16x8*)(Pc + (w * 32 + ni * 16 + l15) * 64 + ks * 32 + quad * 8);
#pragma unroll
        for (int ms = 0; ms < 8; ++ms) {
            bf16x8 af = *(const bf16x8*)(Ac + (ms * 16 + l15) * 64 + ks * 32 + quad * 8);
#pragma unroll
            for (int ni = 0; ni < 2; ++ni)
                g[ms][ni] = __builtin_amdgcn_mfma_f32_16x16x32_bf16(af, bfr[ni], g[ms][ni], 0, 0, 0);
        }
    }
    // mask (keep s<=i) + pack 4 consecutive s -> ds_write_b64
#pragma unroll
    for (int ms = 0; ms < 8; ++ms)
#pragma unroll
        for (int ni = 0; ni < 2; ++ni) {
            int iL = w * 32 + ni * 16 + l15;
            int sBase = ms * 16 + quad * 4;
            f32x4 v = g[ms][ni];
            ushort4 o;
            o.x = (sBase + 0 <= iL) ? f2bf(v[0]) : (ushort)0;
            o.y = (sBase + 1 <= iL) ? f2bf(v[1]) : (ushort)0;
            o.z = (sBase + 2 <= iL) ? f2bf(v[2]) : (ushort)0;
            o.w = (sBase + 3 <= iL) ? f2bf(v[3]) : (ushort)0;
            *(ushort4*)(Gs + iL * 136 + sBase) = o;
        }
    __syncthreads();
    // Phase 2: Y rows i in [w*32, w*32+32)
    const ushort* vtb = VT + (size_t)bh * 128 * 2048 + c * 128;
    const float* sp = S + (size_t)blk * 8192;
    f32x4 y[2][8] = {};
#pragma unroll
    for (int ks = 0; ks < 4; ++ks) {
        bf16x8 af[2];
#pragma unroll
        for (int mi = 0; mi < 2; ++mi)
            af[mi] = *(const bf16x8*)(Gs + (w * 32 + mi * 16 + l15) * 136 + ks * 32 + quad * 8);
#pragma unroll
        for (int nj = 0; nj < 8; ++nj) {
            bf16x8 bfr = *(const bf16x8*)(vtb + (size_t)(nj * 16 + l15) * 2048 + ks * 32 + quad * 8);
#pragma unroll
            for (int mi = 0; mi < 2; ++mi)
                y[mi][nj] = __builtin_amdgcn_mfma_f32_16x16x32_bf16(af[mi], bfr, y[mi][nj], 0, 0, 0);
        }
    }
#pragma unroll
    for (int ks = 0; ks < 2; ++ks) {
        bf16x8 af[2];
#pragma unroll
        for (int mi = 0; mi < 2; ++mi)
            af[mi] = *(const bf16x8*)(Pc + (w * 32 + mi * 16 + l15) * 64 + ks * 32 + quad * 8);
#pragma unroll
        for (int nj = 0; nj < 8; ++nj) {
            const float* s8 = sp + (nj * 16 + l15) * 64 + ks * 32 + quad * 8;
            float4 f0 = *(const float4*)s8;
            float4 f1 = *(const float4*)(s8 + 4);
            bf16x8 bfr;
            bfr[0] = (short)f2bf(f0.x); bfr[1] = (short)f2bf(f0.y);
            bfr[2] = (short)f2bf(f0.z); bfr[3] = (short)f2bf(f0.w);
            bfr[4] = (short)f2bf(f1.x); bfr[5] = (short)f2bf(f1.y);
            bfr[6] = (short)f2bf(f1.z); bfr[7] = (short)f2bf(f1.w);
#pragma unroll
            for (int mi = 0; mi < 2; ++mi)
                y[mi][nj] = __builtin_amdgcn_mfma_f32_16x16x32_bf16(af[mi], bfr, y[mi][nj], 0, 0, 0);
        }
    }
    ushort* yout = Yb + ((size_t)(b * 2048 + c * 128)) * 1024 + h * 128;
#pragma unroll
    for (int mi = 0; mi < 2; ++mi)
#pragma unroll
        for (int nj = 0; nj < 8; ++nj) {
            f32x4 v = y[mi][nj];
#pragma unroll
            for (int r = 0; r < 4; ++r) {
                int iL = w * 32 + mi * 16 + quad * 4 + r;
                yout[(size_t)iL * 1024 + nj * 16 + l15] = f2bf(v[r]);
            }
        }
}

extern "C" void kernel_launch(void* const* d_in, const int* in_sizes, int n_in,
                              void* d_out, int out_size, void* d_ws, size_t ws_size,
                              hipStream_t stream) {
    const float* X  = (const float*)d_in[0];
    const float* Wk = (const float*)d_in[1];
    const float* Wq = (const float*)d_in[2];
    const float* Wv = (const float*)d_in[3];
    const float* Wo = (const float*)d_in[4];
    float* ws = (float*)d_ws;
    // float-unit offsets; total 24,641,536 fu = 98.6 MB
    ushort* Xb  = (ushort*)ws;                  // bf16 X [8192,1024]; reused as Yb
    float*  Q   = ws + 4194304;                 // fp32 Qs [8192,512]
    float*  Kb  = ws + 8388608;                 // fp32 K; reused as S [512][128][64]
    ushort* VT  = (ushort*)(ws + 12582912);     // bf16 VT [32][128][2048]
    ushort* ab  = (ushort*)(ws + 16777216);     // bf16 a  [32][2048][64]
    ushort* aT  = (ushort*)(ws + 18874368);     // bf16 aT [32][64][2048]
    ushort* Pb  = (ushort*)(ws + 20971520);     // bf16 P  [32][2048][64]
    ushort* WqT = (ushort*)(ws + 23068672);
    ushort* WkT = (ushort*)(ws + 23330816);
    ushort* WvT = (ushort*)(ws + 23592960);
    ushort* WoT = (ushort*)(ws + 24117248);
    float* Sb = Kb;
    ushort* Yb = Xb;
    float* out = (float*)d_out;
    float* mbuf = out;            // prep scratch in d_out (overwritten by final GEMM)
    float* sbuf = out + 32768;
    float* Mbuf = out + 65536;
    float* A0b  = out + 67584;

    dim3 blk(256);
    cast_x_kernel<<<8192, blk, 0, stream>>>(X, Xb);
    transpose_cast_kernel<<<dim3(16, 32), blk, 0, stream>>>(Wq, WqT, 1024, 512);
    transpose_cast_kernel<<<dim3(16, 32), blk, 0, stream>>>(Wk, WkT, 1024, 512);
    transpose_cast_kernel<<<dim3(32, 32), blk, 0, stream>>>(Wv, WvT, 1024, 1024);
    transpose_cast_kernel<<<dim3(32, 32), blk, 0, stream>>>(Wo, WoT, 1024, 1024);
    mfma_gemm<0><<<dim3(4, 64), blk, 0, stream>>>(Xb, WqT, Q, nullptr, 8192, 512, 1024);
    mfma_gemm<0><<<dim3(4, 64), blk, 0, stream>>>(Xb, WkT, Kb, nullptr, 8192, 512, 1024);
    mfma_gemm<2><<<dim3(8, 64), blk, 0, stream>>>(Xb, WvT, nullptr, VT, 8192, 1024, 1024);
    softmax64_kernel<<<16384, blk, 0, stream>>>(Q, 65536);
    prep_chunkstats_kernel<<<128, blk, 0, stream>>>(Kb, mbuf, sbuf);
    prep_combine_kernel<<<8, blk, 0, stream>>>(mbuf, sbuf, Mbuf, A0b);
    prep_scan2_kernel<<<128, blk, 0, stream>>>(Kb, Q, Mbuf, A0b, ab, aT, Pb);
    chunk_sums_mfma<<<512, blk, 0, stream>>>(aT, VT, Sb);
    chunk_prefix_kernel<<<1024, blk, 0, stream>>>(Sb);
    chunk_out_mfma<<<512, blk, 0, stream>>>(ab, Pb, VT, Sb, Yb);
    mfma_gemm<0><<<dim3(8, 64), blk, 0, stream>>>(Yb, WoT, out, nullptr, 8192, 1024, 1024);
}

// Round 6
// 285.460 us; speedup vs baseline: 11.7589x; 1.2617x over previous
//
#include <hip/hip_runtime.h>
#include <hip/hip_bf16.h>

// B=4, T=2048, D=1024, L=512, H=8, Lh=64, Dh=128. Chunks: NC=16 of G=128.
// Chunked linear scan as MFMA matmuls:
//   S_c^T[d,l] = sum_t V[t,d] a_t[l]            (chunk_sums_mfma)
//   C0 = exclusive prefix of S over chunks       (chunk_prefix)
//   G^T = A @ P^T, mask s<=i, Y = Gm@V + P@C0    (chunk_out_mfma)
// Prep (a = exp(K-M), A prefix, P = Qs/A) is t-parallel: 512 blocks, 32 t/thread.

typedef __attribute__((ext_vector_type(8))) short bf16x8;
typedef __attribute__((ext_vector_type(4))) float f32x4;

__device__ inline ushort f2bf(float f) {
    unsigned u = __float_as_uint(f);
    unsigned r = (u + 0x7fff + ((u >> 16) & 1)) >> 16;
    return (ushort)r;
}
__device__ inline float bf2f(ushort h) { return __uint_as_float(((unsigned)h) << 16); }

__device__ inline void gload_lds16(const ushort* g, ushort* l) {
    __builtin_amdgcn_global_load_lds((const __attribute__((address_space(1))) void*)g,
                                     (__attribute__((address_space(3))) void*)l, 16, 0, 0);
}

// X fp32 -> bf16, 4 elems/thread.
__global__ __launch_bounds__(256) void cast_x_kernel(const float* __restrict__ X,
                                                     ushort* __restrict__ Xb) {
    int i = blockIdx.x * 1024 + threadIdx.x * 4;
    float4 v = *(const float4*)(X + i);
    ushort4 o = {f2bf(v.x), f2bf(v.y), f2bf(v.z), f2bf(v.w)};
    *(ushort4*)(Xb + i) = o;
}

// All four weights: W [1024,N] fp32 -> WT [N,1024] bf16, 32x32 LDS tiles.
// 3072 tiles: Wq 512, Wk 512, Wv 1024, Wo 1024.
__global__ __launch_bounds__(256) void transpose_all_kernel(const float* __restrict__ Wq,
                                                            const float* __restrict__ Wk,
                                                            const float* __restrict__ Wv,
                                                            const float* __restrict__ Wo,
                                                            ushort* __restrict__ WqT,
                                                            ushort* __restrict__ WkT,
                                                            ushort* __restrict__ WvT,
                                                            ushort* __restrict__ WoT) {
    __shared__ float s[32][33];
    int t = blockIdx.x;
    const float* W; ushort* WT; int N, tile;
    if (t < 512)       { W = Wq; WT = WqT; N = 512;  tile = t; }
    else if (t < 1024) { W = Wk; WT = WkT; N = 512;  tile = t - 512; }
    else if (t < 2048) { W = Wv; WT = WvT; N = 1024; tile = t - 1024; }
    else               { W = Wo; WT = WoT; N = 1024; tile = t - 2048; }
    int tilesX = N >> 5;
    int n0 = (tile % tilesX) * 32, k0 = (tile / tilesX) * 32;
    int tx = threadIdx.x & 31, ty0 = threadIdx.x >> 5;
#pragma unroll
    for (int r = 0; r < 4; ++r) {
        int row = ty0 + r * 8;
        s[row][tx] = W[(size_t)(k0 + row) * N + n0 + tx];
    }
    __syncthreads();
#pragma unroll
    for (int r = 0; r < 4; ++r) {
        int row = ty0 + r * 8;
        WT[(size_t)(n0 + row) * 1024 + k0 + tx] = f2bf(s[tx][row]);
    }
}

// C[M,N] = A[M,K] @ B[K,N]; A bf16 row-major, BT = B^T bf16 [N,K] row-major.
// MODE 0: fp32 C natural. MODE 1: fp32 C with per-row softmax over each wave's
// 64-col stripe (= one head, N=512 only). MODE 2: bf16 VT[bh][d][t] (N=1024).
template <int MODE>
__global__ __launch_bounds__(256) void mfma_gemm(const ushort* __restrict__ A,
                                                 const ushort* __restrict__ BT,
                                                 float* __restrict__ Cf,
                                                 ushort* __restrict__ Cb,
                                                 int M, int N, int K) {
    __shared__ __align__(16) ushort As[128 * 32];
    __shared__ __align__(16) ushort Bs[128 * 32];
    const int tid = threadIdx.x;
    const int w = tid >> 6, lane = tid & 63;
    const int quad = lane >> 4, l15 = lane & 15;
    const int m0 = blockIdx.y * 128, n0 = blockIdx.x * 128;
    const int wm = (w & 1) * 64, wn = (w >> 1) * 64;
    f32x4 acc[4][4] = {};
    const int r0 = tid >> 2, kc = (tid & 3) * 8;
    const int r1 = 64 + r0;
    const ushort* Arow0 = A + (size_t)(m0 + r0) * K + kc;
    const ushort* Arow1 = A + (size_t)(m0 + r1) * K + kc;
    const ushort* Brow0 = BT + (size_t)(n0 + r0) * K + kc;
    const ushort* Brow1 = BT + (size_t)(n0 + r1) * K + kc;
    ushort* AsW0 = As + (w * 64) * 8;
    ushort* AsW1 = As + (256 + w * 64) * 8;
    ushort* BsW0 = Bs + (w * 64) * 8;
    ushort* BsW1 = Bs + (256 + w * 64) * 8;
    const ushort* afp = As + (wm + l15) * 32 + quad * 8;
    const ushort* bfp = Bs + (wn + l15) * 32 + quad * 8;
    for (int k0 = 0; k0 < K; k0 += 32) {
        gload_lds16(Arow0 + k0, AsW0);
        gload_lds16(Arow1 + k0, AsW1);
        gload_lds16(Brow0 + k0, BsW0);
        gload_lds16(Brow1 + k0, BsW1);
        __syncthreads();
        bf16x8 af[4], bf[4];
#pragma unroll
        for (int i = 0; i < 4; ++i) {
            af[i] = *(const bf16x8*)(afp + i * 16 * 32);
            bf[i] = *(const bf16x8*)(bfp + i * 16 * 32);
        }
#pragma unroll
        for (int i = 0; i < 4; ++i)
#pragma unroll
            for (int j = 0; j < 4; ++j)
                acc[i][j] = __builtin_amdgcn_mfma_f32_16x16x32_bf16(af[i], bf[j], acc[i][j], 0, 0, 0);
        __syncthreads();
    }
    if (MODE == 1) {
        // Per output row: softmax over this wave's 64 cols (16 lanes x 4 j).
#pragma unroll
        for (int i = 0; i < 4; ++i)
#pragma unroll
            for (int r = 0; r < 4; ++r) {
                float x0 = acc[i][0][r], x1 = acc[i][1][r];
                float x2 = acc[i][2][r], x3 = acc[i][3][r];
                float m = fmaxf(fmaxf(x0, x1), fmaxf(x2, x3));
#pragma unroll
                for (int off = 1; off < 16; off <<= 1) m = fmaxf(m, __shfl_xor(m, off));
                float e0 = __expf(x0 - m), e1 = __expf(x1 - m);
                float e2 = __expf(x2 - m), e3 = __expf(x3 - m);
                float s = (e0 + e1) + (e2 + e3);
#pragma unroll
                for (int off = 1; off < 16; off <<= 1) s += __shfl_xor(s, off);
                float rs = 1.0f / s;
                acc[i][0][r] = e0 * rs; acc[i][1][r] = e1 * rs;
                acc[i][2][r] = e2 * rs; acc[i][3][r] = e3 * rs;
            }
    }
    const int crow = m0 + wm + quad * 4;
    const int ccol = n0 + wn + l15;
#pragma unroll
    for (int i = 0; i < 4; ++i)
#pragma unroll
        for (int j = 0; j < 4; ++j) {
            f32x4 v = acc[i][j];
            if (MODE == 2) {
                int col = ccol + j * 16;
                int h = col >> 7, dd = col & 127;
                int row = crow + i * 16;
                int bb = row >> 11, t = row & 2047;
                ushort4 o = {f2bf(v[0]), f2bf(v[1]), f2bf(v[2]), f2bf(v[3])};
                *(ushort4*)(Cb + ((size_t)(bb * 8 + h) * 128 + dd) * 2048 + t) = o;
            } else {
#pragma unroll
                for (int r = 0; r < 4; ++r)
                    Cf[(size_t)(crow + i * 16 + r) * N + ccol + j * 16] = v[r];
            }
        }
}

// Block per (bh,c): chunk max + expsum per l. Threads: tg(4) x l(64), 32 t/thread.
__global__ __launch_bounds__(256) void prep_stats_kernel(const float* __restrict__ Kbuf,
                                                         float* __restrict__ mbuf,
                                                         float* __restrict__ sbuf) {
    __shared__ float red[4][64];
    int blk = blockIdx.x, bh = blk >> 4, c = blk & 15;
    int b = bh >> 3, h = bh & 7;
    int tg = threadIdx.x >> 6, l = threadIdx.x & 63;
    const float* kp = Kbuf + ((size_t)(b * 2048 + c * 128 + tg * 32)) * 512 + h * 64 + l;
    float kv[32];
#pragma unroll
    for (int i = 0; i < 32; ++i) kv[i] = kp[(size_t)i * 512];
    float m = kv[0];
#pragma unroll
    for (int i = 1; i < 32; ++i) m = fmaxf(m, kv[i]);
    red[tg][l] = m;
    __syncthreads();
    float M = fmaxf(fmaxf(red[0][l], red[1][l]), fmaxf(red[2][l], red[3][l]));
    float s = 0.f;
#pragma unroll
    for (int i = 0; i < 32; ++i) s += __expf(kv[i] - M);
    __syncthreads();
    red[tg][l] = s;
    __syncthreads();
    if (tg == 0) {
        float S = (red[0][l] + red[1][l]) + (red[2][l] + red[3][l]);
        mbuf[(bh * 16 + c) * 64 + l] = M;
        sbuf[(bh * 16 + c) * 64 + l] = S;
    }
}

// Per (bh,l): combine 16 chunk stats -> global M, exclusive chunk prefix A0.
__global__ __launch_bounds__(256) void prep_combine_kernel(const float* __restrict__ mbuf,
                                                           const float* __restrict__ sbuf,
                                                           float* __restrict__ Mbuf,
                                                           float* __restrict__ A0buf) {
    int gid = blockIdx.x * 256 + threadIdx.x;  // 2048
    int l = gid & 63, bh = gid >> 6;
    float M = -1e30f;
    for (int c = 0; c < 16; ++c) M = fmaxf(M, mbuf[(bh * 16 + c) * 64 + l]);
    float run = 0.f;
    for (int c = 0; c < 16; ++c) {
        A0buf[(bh * 16 + c) * 64 + l] = run;
        run += sbuf[(bh * 16 + c) * 64 + l] * __expf(mbuf[(bh * 16 + c) * 64 + l] - M);
    }
    Mbuf[gid] = M;
}

// Block per (bh,c): a = exp(K-M); A prefix (intra-thread + LDS group scan);
// P = Qs/A. Writes a natural [bh][t][l], aT [bh][l][t], P natural.
__global__ __launch_bounds__(256) void prep_scanP_kernel(const float* __restrict__ Kbuf,
                                                         const float* __restrict__ Qs,
                                                         const float* __restrict__ Mbuf,
                                                         const float* __restrict__ A0buf,
                                                         ushort* __restrict__ abuf,
                                                         ushort* __restrict__ aTbuf,
                                                         ushort* __restrict__ Pbuf) {
    __shared__ float red[4][64];
    int blk = blockIdx.x, bh = blk >> 4, c = blk & 15;
    int b = bh >> 3, h = bh & 7;
    int tg = threadIdx.x >> 6, l = threadIdx.x & 63;
    const float* kp = Kbuf + ((size_t)(b * 2048 + c * 128 + tg * 32)) * 512 + h * 64 + l;
    const float* qp = Qs + ((size_t)(b * 2048 + c * 128 + tg * 32)) * 512 + h * 64 + l;
    float M = Mbuf[bh * 64 + l];
    float a[32];
#pragma unroll
    for (int i = 0; i < 32; ++i) a[i] = __expf(kp[(size_t)i * 512] - M);
    float part = 0.f;
#pragma unroll
    for (int i = 0; i < 32; ++i) part += a[i];
    red[tg][l] = part;
    __syncthreads();
    float A = A0buf[(bh * 16 + c) * 64 + l];
    for (int g = 0; g < 4; ++g) {
        float v = red[g][l];
        A += (g < tg) ? v : 0.f;
    }
    ushort* ap = abuf + ((size_t)(bh * 2048 + c * 128 + tg * 32)) * 64 + l;
    ushort* pp = Pbuf + ((size_t)(bh * 2048 + c * 128 + tg * 32)) * 64 + l;
    ushort atmp[32];
#pragma unroll
    for (int i = 0; i < 32; ++i) {
        A += a[i];
        ushort ab16 = f2bf(a[i]);
        ap[(size_t)i * 64] = ab16;
        atmp[i] = ab16;
        pp[(size_t)i * 64] = f2bf(qp[(size_t)i * 512] / A);
    }
    ushort* atp = aTbuf + ((size_t)bh * 64 + l) * 2048 + c * 128 + tg * 32;
#pragma unroll
    for (int v = 0; v < 4; ++v) *(uint4*)(atp + v * 8) = *(const uint4*)(atmp + v * 8);
}

// Per (bh,c): S^T[d,l] = sum_t V[t,d] a_t[l] via MFMA. S layout [blk][d=128][l=64] fp32.
__global__ __launch_bounds__(256) void chunk_sums_mfma(const ushort* __restrict__ aT,
                                                       const ushort* __restrict__ VT,
                                                       float* __restrict__ S) {
    int blk = blockIdx.x, bh = blk >> 4, c = blk & 15;
    int w = threadIdx.x >> 6, lane = threadIdx.x & 63;
    int quad = lane >> 4, l15 = lane & 15;
    const ushort* vtb = VT + (size_t)bh * 128 * 2048 + c * 128;
    const ushort* atb = aT + (size_t)bh * 64 * 2048 + c * 128;
    f32x4 acc[2][4] = {};
#pragma unroll
    for (int ks = 0; ks < 4; ++ks) {
        bf16x8 af[2];
#pragma unroll
        for (int mi = 0; mi < 2; ++mi)
            af[mi] = *(const bf16x8*)(vtb + (size_t)(w * 32 + mi * 16 + l15) * 2048 + ks * 32 + quad * 8);
#pragma unroll
        for (int nj = 0; nj < 4; ++nj) {
            bf16x8 bfr = *(const bf16x8*)(atb + (size_t)(nj * 16 + l15) * 2048 + ks * 32 + quad * 8);
#pragma unroll
            for (int mi = 0; mi < 2; ++mi)
                acc[mi][nj] = __builtin_amdgcn_mfma_f32_16x16x32_bf16(af[mi], bfr, acc[mi][nj], 0, 0, 0);
        }
    }
    float* sp = S + (size_t)blk * 8192;
#pragma unroll
    for (int mi = 0; mi < 2; ++mi)
#pragma unroll
        for (int nj = 0; nj < 4; ++nj) {
            f32x4 v = acc[mi][nj];
#pragma unroll
            for (int r = 0; r < 4; ++r)
                sp[(w * 32 + mi * 16 + quad * 4 + r) * 64 + nj * 16 + l15] = v[r];
        }
}

// In-place exclusive prefix over the 16 chunks; S layout [bh][c][d][l].
__global__ __launch_bounds__(256) void chunk_prefix_kernel(float* __restrict__ Sbuf) {
    int gid = blockIdx.x * 256 + threadIdx.x;  // 262144
    int l = gid & 63, d = (gid >> 6) & 127, bh = gid >> 13;
    float run = 0.f;
    for (int c = 0; c < 16; ++c) {
        size_t idx = (size_t)(bh * 16 + c) * 8192 + d * 64 + l;
        float t = Sbuf[idx];
        Sbuf[idx] = run;
        run += t;
    }
}

// Per (bh,c): G^T = A @ P^T (C-layout row=s,col=i), mask s<=i, pack to LDS bf16;
// Y = Gm @ V (K=128, b-frag from VT) + P @ C0 (K=64, b-frag from S fp32).
__global__ __launch_bounds__(256) void chunk_out_mfma(const ushort* __restrict__ ab,
                                                      const ushort* __restrict__ Pb,
                                                      const ushort* __restrict__ VT,
                                                      const float* __restrict__ S,
                                                      ushort* __restrict__ Yb) {
    __shared__ __align__(16) ushort Gs[128 * 136];  // [i][s], +8 pad kills conflicts
    int blk = blockIdx.x, bh = blk >> 4, c = blk & 15;
    int b = bh >> 3, h = bh & 7;
    int w = threadIdx.x >> 6, lane = threadIdx.x & 63;
    int quad = lane >> 4, l15 = lane & 15;
    const ushort* Pc = Pb + (size_t)(bh * 2048 + c * 128) * 64;
    const ushort* Ac = ab + (size_t)(bh * 2048 + c * 128) * 64;
    // Phase 1: G^T = A @ P^T for cols i in [w*32, w*32+32)
    f32x4 g[8][2] = {};
#pragma unroll
    for (int ks = 0; ks < 2; ++ks) {
        bf16x8 bfr[2];
#pragma unroll
        for (int ni = 0; ni < 2; ++ni)
            bfr[ni] = *(const bf16x8*)(Pc + (w * 32 + ni * 16 + l15) * 64 + ks * 32 + quad * 8);
#pragma unroll
        for (int ms = 0; ms < 8; ++ms) {
            bf16x8 af = *(const bf16x8*)(Ac + (ms * 16 + l15) * 64 + ks * 32 + quad * 8);
#pragma unroll
            for (int ni = 0; ni < 2; ++ni)
                g[ms][ni] = __builtin_amdgcn_mfma_f32_16x16x32_bf16(af, bfr[ni], g[ms][ni], 0, 0, 0);
        }
    }
#pragma unroll
    for (int ms = 0; ms < 8; ++ms)
#pragma unroll
        for (int ni = 0; ni < 2; ++ni) {
            int iL = w * 32 + ni * 16 + l15;
            int sBase = ms * 16 + quad * 4;
            f32x4 v = g[ms][ni];
            ushort4 o;
            o.x = (sBase + 0 <= iL) ? f2bf(v[0]) : (ushort)0;
            o.y = (sBase + 1 <= iL) ? f2bf(v[1]) : (ushort)0;
            o.z = (sBase + 2 <= iL) ? f2bf(v[2]) : (ushort)0;
            o.w = (sBase + 3 <= iL) ? f2bf(v[3]) : (ushort)0;
            *(ushort4*)(Gs + iL * 136 + sBase) = o;
        }
    __syncthreads();
    // Phase 2: Y rows i in [w*32, w*32+32)
    const ushort* vtb = VT + (size_t)bh * 128 * 2048 + c * 128;
    const float* sp = S + (size_t)blk * 8192;
    f32x4 y[2][8] = {};
#pragma unroll
    for (int ks = 0; ks < 4; ++ks) {
        bf16x8 af[2];
#pragma unroll
        for (int mi = 0; mi < 2; ++mi)
            af[mi] = *(const bf16x8*)(Gs + (w * 32 + mi * 16 + l15) * 136 + ks * 32 + quad * 8);
#pragma unroll
        for (int nj = 0; nj < 8; ++nj) {
            bf16x8 bfr = *(const bf16x8*)(vtb + (size_t)(nj * 16 + l15) * 2048 + ks * 32 + quad * 8);
#pragma unroll
            for (int mi = 0; mi < 2; ++mi)
                y[mi][nj] = __builtin_amdgcn_mfma_f32_16x16x32_bf16(af[mi], bfr, y[mi][nj], 0, 0, 0);
        }
    }
#pragma unroll
    for (int ks = 0; ks < 2; ++ks) {
        bf16x8 af[2];
#pragma unroll
        for (int mi = 0; mi < 2; ++mi)
            af[mi] = *(const bf16x8*)(Pc + (w * 32 + mi * 16 + l15) * 64 + ks * 32 + quad * 8);
#pragma unroll
        for (int nj = 0; nj < 8; ++nj) {
            const float* s8 = sp + (nj * 16 + l15) * 64 + ks * 32 + quad * 8;
            float4 f0 = *(const float4*)s8;
            float4 f1 = *(const float4*)(s8 + 4);
            bf16x8 bfr;
            bfr[0] = (short)f2bf(f0.x); bfr[1] = (short)f2bf(f0.y);
            bfr[2] = (short)f2bf(f0.z); bfr[3] = (short)f2bf(f0.w);
            bfr[4] = (short)f2bf(f1.x); bfr[5] = (short)f2bf(f1.y);
            bfr[6] = (short)f2bf(f1.z); bfr[7] = (short)f2bf(f1.w);
#pragma unroll
            for (int mi = 0; mi < 2; ++mi)
                y[mi][nj] = __builtin_amdgcn_mfma_f32_16x16x32_bf16(af[mi], bfr, y[mi][nj], 0, 0, 0);
        }
    }
    ushort* yout = Yb + ((size_t)(b * 2048 + c * 128)) * 1024 + h * 128;
#pragma unroll
    for (int mi = 0; mi < 2; ++mi)
#pragma unroll
        for (int nj = 0; nj < 8; ++nj) {
            f32x4 v = y[mi][nj];
#pragma unroll
            for (int r = 0; r < 4; ++r) {
                int iL = w * 32 + mi * 16 + quad * 4 + r;
                yout[(size_t)iL * 1024 + nj * 16 + l15] = f2bf(v[r]);
            }
        }
}

extern "C" void kernel_launch(void* const* d_in, const int* in_sizes, int n_in,
                              void* d_out, int out_size, void* d_ws, size_t ws_size,
                              hipStream_t stream) {
    const float* X  = (const float*)d_in[0];
    const float* Wk = (const float*)d_in[1];
    const float* Wq = (const float*)d_in[2];
    const float* Wv = (const float*)d_in[3];
    const float* Wo = (const float*)d_in[4];
    float* ws = (float*)d_ws;
    // float-unit offsets; total 24,641,536 fu = 98.6 MB
    ushort* Xb  = (ushort*)ws;                  // bf16 X [8192,1024]; reused as Yb
    float*  Q   = ws + 4194304;                 // fp32 softmaxed Qs [8192,512]
    float*  Kb  = ws + 8388608;                 // fp32 K; reused as S [512][128][64]
    ushort* VT  = (ushort*)(ws + 12582912);     // bf16 VT [32][128][2048]
    ushort* ab  = (ushort*)(ws + 16777216);     // bf16 a  [32][2048][64]
    ushort* aT  = (ushort*)(ws + 18874368);     // bf16 aT [32][64][2048]
    ushort* Pb  = (ushort*)(ws + 20971520);     // bf16 P  [32][2048][64]
    ushort* WqT = (ushort*)(ws + 23068672);
    ushort* WkT = (ushort*)(ws + 23330816);
    ushort* WvT = (ushort*)(ws + 23592960);
    ushort* WoT = (ushort*)(ws + 24117248);
    float* Sb = Kb;
    ushort* Yb = Xb;
    float* out = (float*)d_out;
    float* mbuf = out;            // prep scratch in d_out (overwritten by final GEMM)
    float* sbuf = out + 32768;
    float* Mbuf = out + 65536;
    float* A0b  = out + 67584;

    dim3 blk(256);
    cast_x_kernel<<<8192, blk, 0, stream>>>(X, Xb);
    transpose_all_kernel<<<3072, blk, 0, stream>>>(Wq, Wk, Wv, Wo, WqT, WkT, WvT, WoT);
    mfma_gemm<1><<<dim3(4, 64), blk, 0, stream>>>(Xb, WqT, Q, nullptr, 8192, 512, 1024);
    mfma_gemm<0><<<dim3(4, 64), blk, 0, stream>>>(Xb, WkT, Kb, nullptr, 8192, 512, 1024);
    mfma_gemm<2><<<dim3(8, 64), blk, 0, stream>>>(Xb, WvT, nullptr, VT, 8192, 1024, 1024);
    prep_stats_kernel<<<512, blk, 0, stream>>>(Kb, mbuf, sbuf);
    prep_combine_kernel<<<8, blk, 0, stream>>>(mbuf, sbuf, Mbuf, A0b);
    prep_scanP_kernel<<<512, blk, 0, stream>>>(Kb, Q, Mbuf, A0b, ab, aT, Pb);
    chunk_sums_mfma<<<512, blk, 0, stream>>>(aT, VT, Sb);
    chunk_prefix_kernel<<<1024, blk, 0, stream>>>(Sb);
    chunk_out_mfma<<<512, blk, 0, stream>>>(ab, Pb, VT, Sb, Yb);
    mfma_gemm<0><<<dim3(8, 64), blk, 0, stream>>>(Yb, WoT, out, nullptr, 8192, 1024, 1024);
}

// Round 7
// 243.538 us; speedup vs baseline: 13.7830x; 1.1721x over previous
//
#include <hip/hip_runtime.h>
#include <hip/hip_bf16.h>

// B=4, T=2048, D=1024, L=512, H=8, Lh=64, Dh=128. Chunks: NC=16 of G=128.
// 8-launch pipeline:
//  1 prep_inputs: X->bf16, W->W^T bf16 (WqkT = [WqT;WkT] concatenated)
//  2 qk_gemm:  [Qs|K] = X@[Wq|Wk]; epilogue: softmax->Qs bf16 | chunk stats + K bf16
//  3 vt_gemm:  VT[bh][d][t] = (X@Wv)^T via LDS-transposed epilogue
//  4 prep_scanP: combine stats -> M,A0; a=exp(K-M), A prefix, P=Qs/A (bf16 a,aT,P)
//  5 chunk_sums_mfma: S_c^T[d,l] = sum_t V[t,d] a_t[l]
//  6 chunk_prefix: exclusive prefix of S over chunks
//  7 chunk_out_mfma: G^T=A@P^T, mask, Y = Gm@V + P@C0
//  8 mfma_gemm: out = Y@Wo (fp32 out)

typedef __attribute__((ext_vector_type(8))) short bf16x8;
typedef __attribute__((ext_vector_type(4))) float f32x4;

__device__ inline ushort f2bf(float f) {
    unsigned u = __float_as_uint(f);
    unsigned r = (u + 0x7fff + ((u >> 16) & 1)) >> 16;
    return (ushort)r;
}
__device__ inline float bf2f(ushort h) { return __uint_as_float(((unsigned)h) << 16); }

__device__ inline void gload_lds16(const ushort* g, ushort* l) {
    __builtin_amdgcn_global_load_lds((const __attribute__((address_space(1))) void*)g,
                                     (__attribute__((address_space(3))) void*)l, 16, 0, 0);
}

// blocks [0,8192): X fp32 -> bf16. blocks [8192,11264): weight transpose tiles.
__global__ __launch_bounds__(256) void prep_inputs_kernel(const float* __restrict__ X,
                                                          const float* __restrict__ Wq,
                                                          const float* __restrict__ Wk,
                                                          const float* __restrict__ Wv,
                                                          const float* __restrict__ Wo,
                                                          ushort* __restrict__ Xb,
                                                          ushort* __restrict__ WqkT,
                                                          ushort* __restrict__ WvT,
                                                          ushort* __restrict__ WoT) {
    if (blockIdx.x < 8192) {
        int i = blockIdx.x * 1024 + threadIdx.x * 4;
        float4 v = *(const float4*)(X + i);
        ushort4 o = {f2bf(v.x), f2bf(v.y), f2bf(v.z), f2bf(v.w)};
        *(ushort4*)(Xb + i) = o;
        return;
    }
    __shared__ float s[32][33];
    int t = blockIdx.x - 8192;
    const float* W; ushort* WT; int N, tile, rowoff;
    if (t < 512)       { W = Wq; WT = WqkT; N = 512;  tile = t;        rowoff = 0; }
    else if (t < 1024) { W = Wk; WT = WqkT; N = 512;  tile = t - 512;  rowoff = 512; }
    else if (t < 2048) { W = Wv; WT = WvT;  N = 1024; tile = t - 1024; rowoff = 0; }
    else               { W = Wo; WT = WoT;  N = 1024; tile = t - 2048; rowoff = 0; }
    int tilesX = N >> 5;
    int n0 = (tile % tilesX) * 32, k0 = (tile / tilesX) * 32;
    int tx = threadIdx.x & 31, ty0 = threadIdx.x >> 5;
#pragma unroll
    for (int r = 0; r < 4; ++r) {
        int row = ty0 + r * 8;
        s[row][tx] = W[(size_t)(k0 + row) * N + n0 + tx];
    }
    __syncthreads();
#pragma unroll
    for (int r = 0; r < 4; ++r) {
        int row = ty0 + r * 8;
        WT[(size_t)(rowoff + n0 + row) * 1024 + k0 + tx] = f2bf(s[tx][row]);
    }
}

// Combined Q|K GEMM: M=8192, N=1024 (cols 0..511 Q, 512..1023 K), K=1024.
// Q blocks: softmax over each wave's 64-col head stripe -> Qs bf16 natural.
// K blocks: chunk stats (block's 128 rows = one chunk) -> mbuf/sbuf; K bf16 natural.
__global__ __launch_bounds__(256) void qk_gemm(const ushort* __restrict__ A,
                                               const ushort* __restrict__ BT,
                                               ushort* __restrict__ Qb,
                                               ushort* __restrict__ Kbp,
                                               float* __restrict__ mbuf,
                                               float* __restrict__ sbuf) {
    __shared__ __align__(16) ushort As[128 * 32];
    __shared__ __align__(16) ushort Bs[128 * 32];
    __shared__ float sredM[2][128];
    __shared__ float sredS[2][128];
    const int K = 1024;
    const int tid = threadIdx.x;
    const int w = tid >> 6, lane = tid & 63;
    const int quad = lane >> 4, l15 = lane & 15;
    const int m0 = blockIdx.y * 128, n0 = blockIdx.x * 128;
    const int wm = (w & 1) * 64, wn = (w >> 1) * 64;
    f32x4 acc[4][4] = {};
    const int r0 = tid >> 2, kc = (tid & 3) * 8;
    const int r1 = 64 + r0;
    const ushort* Arow0 = A + (size_t)(m0 + r0) * K + kc;
    const ushort* Arow1 = A + (size_t)(m0 + r1) * K + kc;
    const ushort* Brow0 = BT + (size_t)(n0 + r0) * K + kc;
    const ushort* Brow1 = BT + (size_t)(n0 + r1) * K + kc;
    ushort* AsW0 = As + (w * 64) * 8;
    ushort* AsW1 = As + (256 + w * 64) * 8;
    ushort* BsW0 = Bs + (w * 64) * 8;
    ushort* BsW1 = Bs + (256 + w * 64) * 8;
    const ushort* afp = As + (wm + l15) * 32 + quad * 8;
    const ushort* bfp = Bs + (wn + l15) * 32 + quad * 8;
    for (int k0 = 0; k0 < K; k0 += 32) {
        gload_lds16(Arow0 + k0, AsW0);
        gload_lds16(Arow1 + k0, AsW1);
        gload_lds16(Brow0 + k0, BsW0);
        gload_lds16(Brow1 + k0, BsW1);
        __syncthreads();
        bf16x8 af[4], bf[4];
#pragma unroll
        for (int i = 0; i < 4; ++i) {
            af[i] = *(const bf16x8*)(afp + i * 16 * 32);
            bf[i] = *(const bf16x8*)(bfp + i * 16 * 32);
        }
#pragma unroll
        for (int i = 0; i < 4; ++i)
#pragma unroll
            for (int j = 0; j < 4; ++j)
                acc[i][j] = __builtin_amdgcn_mfma_f32_16x16x32_bf16(af[i], bf[j], acc[i][j], 0, 0, 0);
        __syncthreads();
    }
    const int crow = m0 + wm + quad * 4;
    const int ccol = n0 + wn + l15;
    if (n0 < 512) {
        // softmax per row over this wave's 64-col stripe (= one head)
#pragma unroll
        for (int i = 0; i < 4; ++i)
#pragma unroll
            for (int r = 0; r < 4; ++r) {
                float x0 = acc[i][0][r], x1 = acc[i][1][r];
                float x2 = acc[i][2][r], x3 = acc[i][3][r];
                float m = fmaxf(fmaxf(x0, x1), fmaxf(x2, x3));
#pragma unroll
                for (int off = 1; off < 16; off <<= 1) m = fmaxf(m, __shfl_xor(m, off));
                float e0 = __expf(x0 - m), e1 = __expf(x1 - m);
                float e2 = __expf(x2 - m), e3 = __expf(x3 - m);
                float s = (e0 + e1) + (e2 + e3);
#pragma unroll
                for (int off = 1; off < 16; off <<= 1) s += __shfl_xor(s, off);
                float rs = 1.0f / s;
                acc[i][0][r] = e0 * rs; acc[i][1][r] = e1 * rs;
                acc[i][2][r] = e2 * rs; acc[i][3][r] = e3 * rs;
            }
#pragma unroll
        for (int i = 0; i < 4; ++i)
#pragma unroll
            for (int j = 0; j < 4; ++j) {
                f32x4 v = acc[i][j];
#pragma unroll
                for (int r = 0; r < 4; ++r)
                    Qb[(size_t)(crow + i * 16 + r) * 512 + ccol + j * 16] = f2bf(v[r]);
            }
    } else {
        // chunk stats over this block's 128 rows (= chunk c of batch b)
        int b = blockIdx.y >> 4, c = blockIdx.y & 15;
        float mj[4];
#pragma unroll
        for (int j = 0; j < 4; ++j) {
            float m = -1e30f;
#pragma unroll
            for (int i = 0; i < 4; ++i)
#pragma unroll
                for (int r = 0; r < 4; ++r) m = fmaxf(m, acc[i][j][r]);
            m = fmaxf(m, __shfl_xor(m, 16));
            m = fmaxf(m, __shfl_xor(m, 32));
            mj[j] = m;
        }
        if (quad == 0)
#pragma unroll
            for (int j = 0; j < 4; ++j) sredM[w & 1][(w >> 1) * 64 + j * 16 + l15] = mj[j];
        __syncthreads();
#pragma unroll
        for (int j = 0; j < 4; ++j) {
            int ci = (w >> 1) * 64 + j * 16 + l15;
            float M = fmaxf(sredM[0][ci], sredM[1][ci]);
            float s = 0.f;
#pragma unroll
            for (int i = 0; i < 4; ++i)
#pragma unroll
                for (int r = 0; r < 4; ++r) s += __expf(acc[i][j][r] - M);
            s += __shfl_xor(s, 16);
            s += __shfl_xor(s, 32);
            mj[j] = s;
        }
        if (quad == 0)
#pragma unroll
            for (int j = 0; j < 4; ++j) sredS[w & 1][(w >> 1) * 64 + j * 16 + l15] = mj[j];
        __syncthreads();
        if (tid < 128) {
            int Kcol = (n0 - 512) + tid;
            int h = Kcol >> 6, l = Kcol & 63;
            int idx = (((b * 8 + h) * 16 + c)) * 64 + l;
            mbuf[idx] = fmaxf(sredM[0][tid], sredM[1][tid]);
            sbuf[idx] = sredS[0][tid] + sredS[1][tid];
        }
#pragma unroll
        for (int i = 0; i < 4; ++i)
#pragma unroll
            for (int j = 0; j < 4; ++j) {
                f32x4 v = acc[i][j];
#pragma unroll
                for (int r = 0; r < 4; ++r)
                    Kbp[(size_t)(crow + i * 16 + r) * 512 + (ccol - 512) + j * 16] = f2bf(v[r]);
            }
    }
}

// V GEMM: M=8192, N=1024, K=1024; epilogue transposes tile through LDS and
// writes VT[bh][d][t] bf16 with 256B-contiguous runs. Block cols = one head.
__global__ __launch_bounds__(256) void vt_gemm(const ushort* __restrict__ A,
                                               const ushort* __restrict__ BT,
                                               ushort* __restrict__ VT) {
    __shared__ __align__(16) ushort As[128 * 32];
    __shared__ __align__(16) ushort Bs[128 * 32];
    __shared__ __align__(16) ushort Ts[128 * 136];
    const int K = 1024;
    const int tid = threadIdx.x;
    const int w = tid >> 6, lane = tid & 63;
    const int quad = lane >> 4, l15 = lane & 15;
    const int m0 = blockIdx.y * 128, n0 = blockIdx.x * 128;
    const int wm = (w & 1) * 64, wn = (w >> 1) * 64;
    f32x4 acc[4][4] = {};
    const int r0 = tid >> 2, kc = (tid & 3) * 8;
    const int r1 = 64 + r0;
    const ushort* Arow0 = A + (size_t)(m0 + r0) * K + kc;
    const ushort* Arow1 = A + (size_t)(m0 + r1) * K + kc;
    const ushort* Brow0 = BT + (size_t)(n0 + r0) * K + kc;
    const ushort* Brow1 = BT + (size_t)(n0 + r1) * K + kc;
    ushort* AsW0 = As + (w * 64) * 8;
    ushort* AsW1 = As + (256 + w * 64) * 8;
    ushort* BsW0 = Bs + (w * 64) * 8;
    ushort* BsW1 = Bs + (256 + w * 64) * 8;
    const ushort* afp = As + (wm + l15) * 32 + quad * 8;
    const ushort* bfp = Bs + (wn + l15) * 32 + quad * 8;
    for (int k0 = 0; k0 < K; k0 += 32) {
        gload_lds16(Arow0 + k0, AsW0);
        gload_lds16(Arow1 + k0, AsW1);
        gload_lds16(Brow0 + k0, BsW0);
        gload_lds16(Brow1 + k0, BsW1);
        __syncthreads();
        bf16x8 af[4], bf[4];
#pragma unroll
        for (int i = 0; i < 4; ++i) {
            af[i] = *(const bf16x8*)(afp + i * 16 * 32);
            bf[i] = *(const bf16x8*)(bfp + i * 16 * 32);
        }
#pragma unroll
        for (int i = 0; i < 4; ++i)
#pragma unroll
            for (int j = 0; j < 4; ++j)
                acc[i][j] = __builtin_amdgcn_mfma_f32_16x16x32_bf16(af[i], bf[j], acc[i][j], 0, 0, 0);
        __syncthreads();
    }
    // Ts[d][t] (trow=136): d = block col, t = block row
#pragma unroll
    for (int i = 0; i < 4; ++i)
#pragma unroll
        for (int j = 0; j < 4; ++j) {
            f32x4 v = acc[i][j];
            int d = wn + j * 16 + l15;
            int t = wm + i * 16 + quad * 4;
            ushort4 o = {f2bf(v[0]), f2bf(v[1]), f2bf(v[2]), f2bf(v[3])};
            *(ushort4*)(Ts + d * 136 + t) = o;
        }
    __syncthreads();
    int b = m0 >> 11, tloc = m0 & 2047, h = n0 >> 7;
    ushort* base = VT + ((size_t)(b * 8 + h) * 128) * 2048 + tloc;
    int kk = tid & 7;
#pragma unroll
    for (int p = 0; p < 4; ++p) {
        int dd = p * 32 + (tid >> 3);
        const uint4* src = (const uint4*)(Ts + dd * 136 + kk * 16);
        uint4* dst = (uint4*)(base + (size_t)dd * 2048 + kk * 16);
        dst[0] = src[0];
        dst[1] = src[1];
    }
}

// Block per (bh,c): combine stats (M, A0) inline; a = exp(K-M); A prefix;
// P = Qs/A. K, Qs bf16 natural. Writes a natural, aT [bh][l][t], P natural.
__global__ __launch_bounds__(256) void prep_scanP_kernel(const ushort* __restrict__ Kbuf,
                                                         const ushort* __restrict__ Qs,
                                                         const float* __restrict__ mbuf,
                                                         const float* __restrict__ sbuf,
                                                         ushort* __restrict__ abuf,
                                                         ushort* __restrict__ aTbuf,
                                                         ushort* __restrict__ Pbuf) {
    __shared__ float red[4][64];
    int blk = blockIdx.x, bh = blk >> 4, c = blk & 15;
    int b = bh >> 3, h = bh & 7;
    int tg = threadIdx.x >> 6, l = threadIdx.x & 63;
    float mc[16];
#pragma unroll
    for (int cc = 0; cc < 16; ++cc) mc[cc] = mbuf[(bh * 16 + cc) * 64 + l];
    float M = -1e30f;
#pragma unroll
    for (int cc = 0; cc < 16; ++cc) M = fmaxf(M, mc[cc]);
    float A0 = 0.f;
    for (int cc = 0; cc < c; ++cc) A0 += sbuf[(bh * 16 + cc) * 64 + l] * __expf(mc[cc] - M);
    const ushort* kp = Kbuf + ((size_t)(b * 2048 + c * 128 + tg * 32)) * 512 + h * 64 + l;
    const ushort* qp = Qs + ((size_t)(b * 2048 + c * 128 + tg * 32)) * 512 + h * 64 + l;
    float a[32];
#pragma unroll
    for (int i = 0; i < 32; ++i) a[i] = __expf(bf2f(kp[(size_t)i * 512]) - M);
    float part = 0.f;
#pragma unroll
    for (int i = 0; i < 32; ++i) part += a[i];
    red[tg][l] = part;
    __syncthreads();
    float A = A0;
    for (int g = 0; g < 4; ++g) {
        float v = red[g][l];
        A += (g < tg) ? v : 0.f;
    }
    ushort* ap = abuf + ((size_t)(bh * 2048 + c * 128 + tg * 32)) * 64 + l;
    ushort* pp = Pbuf + ((size_t)(bh * 2048 + c * 128 + tg * 32)) * 64 + l;
    ushort atmp[32];
#pragma unroll
    for (int i = 0; i < 32; ++i) {
        A += a[i];
        ushort ab16 = f2bf(a[i]);
        ap[(size_t)i * 64] = ab16;
        atmp[i] = ab16;
        pp[(size_t)i * 64] = f2bf(bf2f(qp[(size_t)i * 512]) / A);
    }
    ushort* atp = aTbuf + ((size_t)bh * 64 + l) * 2048 + c * 128 + tg * 32;
#pragma unroll
    for (int v = 0; v < 4; ++v) *(uint4*)(atp + v * 8) = *(const uint4*)(atmp + v * 8);
}

// Per (bh,c): S^T[d,l] = sum_t V[t,d] a_t[l] via MFMA. S layout [blk][d=128][l=64] fp32.
__global__ __launch_bounds__(256) void chunk_sums_mfma(const ushort* __restrict__ aT,
                                                       const ushort* __restrict__ VT,
                                                       float* __restrict__ S) {
    int blk = blockIdx.x, bh = blk >> 4, c = blk & 15;
    int w = threadIdx.x >> 6, lane = threadIdx.x & 63;
    int quad = lane >> 4, l15 = lane & 15;
    const ushort* vtb = VT + (size_t)bh * 128 * 2048 + c * 128;
    const ushort* atb = aT + (size_t)bh * 64 * 2048 + c * 128;
    f32x4 acc[2][4] = {};
#pragma unroll
    for (int ks = 0; ks < 4; ++ks) {
        bf16x8 af[2];
#pragma unroll
        for (int mi = 0; mi < 2; ++mi)
            af[mi] = *(const bf16x8*)(vtb + (size_t)(w * 32 + mi * 16 + l15) * 2048 + ks * 32 + quad * 8);
#pragma unroll
        for (int nj = 0; nj < 4; ++nj) {
            bf16x8 bfr = *(const bf16x8*)(atb + (size_t)(nj * 16 + l15) * 2048 + ks * 32 + quad * 8);
#pragma unroll
            for (int mi = 0; mi < 2; ++mi)
                acc[mi][nj] = __builtin_amdgcn_mfma_f32_16x16x32_bf16(af[mi], bfr, acc[mi][nj], 0, 0, 0);
        }
    }
    float* sp = S + (size_t)blk * 8192;
#pragma unroll
    for (int mi = 0; mi < 2; ++mi)
#pragma unroll
        for (int nj = 0; nj < 4; ++nj) {
            f32x4 v = acc[mi][nj];
#pragma unroll
            for (int r = 0; r < 4; ++r)
                sp[(w * 32 + mi * 16 + quad * 4 + r) * 64 + nj * 16 + l15] = v[r];
        }
}

// In-place exclusive prefix over the 16 chunks; S layout [bh][c][d][l].
__global__ __launch_bounds__(256) void chunk_prefix_kernel(float* __restrict__ Sbuf) {
    int gid = blockIdx.x * 256 + threadIdx.x;  // 262144
    int l = gid & 63, d = (gid >> 6) & 127, bh = gid >> 13;
    float run = 0.f;
    for (int c = 0; c < 16; ++c) {
        size_t idx = (size_t)(bh * 16 + c) * 8192 + d * 64 + l;
        float t = Sbuf[idx];
        Sbuf[idx] = run;
        run += t;
    }
}

// Per (bh,c): G^T = A @ P^T (C-layout row=s,col=i), mask s<=i, pack to LDS bf16;
// Y = Gm @ V (K=128, b-frag from VT) + P @ C0 (K=64, b-frag from S fp32).
__global__ __launch_bounds__(256) void chunk_out_mfma(const ushort* __restrict__ ab,
                                                      const ushort* __restrict__ Pb,
                                                      const ushort* __restrict__ VT,
                                                      const float* __restrict__ S,
                                                      ushort* __restrict__ Yb) {
    __shared__ __align__(16) ushort Gs[128 * 136];  // [i][s], +8 pad kills conflicts
    int blk = blockIdx.x, bh = blk >> 4, c = blk & 15;
    int b = bh >> 3, h = bh & 7;
    int w = threadIdx.x >> 6, lane = threadIdx.x & 63;
    int quad = lane >> 4, l15 = lane & 15;
    const ushort* Pc = Pb + (size_t)(bh * 2048 + c * 128) * 64;
    const ushort* Ac = ab + (size_t)(bh * 2048 + c * 128) * 64;
    // Phase 1: G^T = A @ P^T for cols i in [w*32, w*32+32)
    f32x4 g[8][2] = {};
#pragma unroll
    for (int ks = 0; ks < 2; ++ks) {
        bf16x8 bfr[2];
#pragma unroll
        for (int ni = 0; ni < 2; ++ni)
            bfr[ni] = *(const bf16x8*)(Pc + (w * 32 + ni * 16 + l15) * 64 + ks * 32 + quad * 8);
#pragma unroll
        for (int ms = 0; ms < 8; ++ms) {
            bf16x8 af = *(const bf16x8*)(Ac + (ms * 16 + l15) * 64 + ks * 32 + quad * 8);
#pragma unroll
            for (int ni = 0; ni < 2; ++ni)
                g[ms][ni] = __builtin_amdgcn_mfma_f32_16x16x32_bf16(af, bfr[ni], g[ms][ni], 0, 0, 0);
        }
    }
#pragma unroll
    for (int ms = 0; ms < 8; ++ms)
#pragma unroll
        for (int ni = 0; ni < 2; ++ni) {
            int iL = w * 32 + ni * 16 + l15;
            int sBase = ms * 16 + quad * 4;
            f32x4 v = g[ms][ni];
            ushort4 o;
            o.x = (sBase + 0 <= iL) ? f2bf(v[0]) : (ushort)0;
            o.y = (sBase + 1 <= iL) ? f2bf(v[1]) : (ushort)0;
            o.z = (sBase + 2 <= iL) ? f2bf(v[2]) : (ushort)0;
            o.w = (sBase + 3 <= iL) ? f2bf(v[3]) : (ushort)0;
            *(ushort4*)(Gs + iL * 136 + sBase) = o;
        }
    __syncthreads();
    // Phase 2: Y rows i in [w*32, w*32+32)
    const ushort* vtb = VT + (size_t)bh * 128 * 2048 + c * 128;
    const float* sp = S + (size_t)blk * 8192;
    f32x4 y[2][8] = {};
#pragma unroll
    for (int ks = 0; ks < 4; ++ks) {
        bf16x8 af[2];
#pragma unroll
        for (int mi = 0; mi < 2; ++mi)
            af[mi] = *(const bf16x8*)(Gs + (w * 32 + mi * 16 + l15) * 136 + ks * 32 + quad * 8);
#pragma unroll
        for (int nj = 0; nj < 8; ++nj) {
            bf16x8 bfr = *(const bf16x8*)(vtb + (size_t)(nj * 16 + l15) * 2048 + ks * 32 + quad * 8);
#pragma unroll
            for (int mi = 0; mi < 2; ++mi)
                y[mi][nj] = __builtin_amdgcn_mfma_f32_16x16x32_bf16(af[mi], bfr, y[mi][nj], 0, 0, 0);
        }
    }
#pragma unroll
    for (int ks = 0; ks < 2; ++ks) {
        bf16x8 af[2];
#pragma unroll
        for (int mi = 0; mi < 2; ++mi)
            af[mi] = *(const bf16x8*)(Pc + (w * 32 + mi * 16 + l15) * 64 + ks * 32 + quad * 8);
#pragma unroll
        for (int nj = 0; nj < 8; ++nj) {
            const float* s8 = sp + (nj * 16 + l15) * 64 + ks * 32 + quad * 8;
            float4 f0 = *(const float4*)s8;
            float4 f1 = *(const float4*)(s8 + 4);
            bf16x8 bfr;
            bfr[0] = (short)f2bf(f0.x); bfr[1] = (short)f2bf(f0.y);
            bfr[2] = (short)f2bf(f0.z); bfr[3] = (short)f2bf(f0.w);
            bfr[4] = (short)f2bf(f1.x); bfr[5] = (short)f2bf(f1.y);
            bfr[6] = (short)f2bf(f1.z); bfr[7] = (short)f2bf(f1.w);
#pragma unroll
            for (int mi = 0; mi < 2; ++mi)
                y[mi][nj] = __builtin_amdgcn_mfma_f32_16x16x32_bf16(af[mi], bfr, y[mi][nj], 0, 0, 0);
        }
    }
    ushort* yout = Yb + ((size_t)(b * 2048 + c * 128)) * 1024 + h * 128;
#pragma unroll
    for (int mi = 0; mi < 2; ++mi)
#pragma unroll
        for (int nj = 0; nj < 8; ++nj) {
            f32x4 v = y[mi][nj];
#pragma unroll
            for (int r = 0; r < 4; ++r) {
                int iL = w * 32 + mi * 16 + quad * 4 + r;
                yout[(size_t)iL * 1024 + nj * 16 + l15] = f2bf(v[r]);
            }
        }
}

// Plain GEMM, fp32 C natural (final out = Y @ Wo).
__global__ __launch_bounds__(256) void mfma_gemm(const ushort* __restrict__ A,
                                                 const ushort* __restrict__ BT,
                                                 float* __restrict__ Cf,
                                                 int M, int N, int K) {
    __shared__ __align__(16) ushort As[128 * 32];
    __shared__ __align__(16) ushort Bs[128 * 32];
    const int tid = threadIdx.x;
    const int w = tid >> 6, lane = tid & 63;
    const int quad = lane >> 4, l15 = lane & 15;
    const int m0 = blockIdx.y * 128, n0 = blockIdx.x * 128;
    const int wm = (w & 1) * 64, wn = (w >> 1) * 64;
    f32x4 acc[4][4] = {};
    const int r0 = tid >> 2, kc = (tid & 3) * 8;
    const int r1 = 64 + r0;
    const ushort* Arow0 = A + (size_t)(m0 + r0) * K + kc;
    const ushort* Arow1 = A + (size_t)(m0 + r1) * K + kc;
    const ushort* Brow0 = BT + (size_t)(n0 + r0) * K + kc;
    const ushort* Brow1 = BT + (size_t)(n0 + r1) * K + kc;
    ushort* AsW0 = As + (w * 64) * 8;
    ushort* AsW1 = As + (256 + w * 64) * 8;
    ushort* BsW0 = Bs + (w * 64) * 8;
    ushort* BsW1 = Bs + (256 + w * 64) * 8;
    const ushort* afp = As + (wm + l15) * 32 + quad * 8;
    const ushort* bfp = Bs + (wn + l15) * 32 + quad * 8;
    for (int k0 = 0; k0 < K; k0 += 32) {
        gload_lds16(Arow0 + k0, AsW0);
        gload_lds16(Arow1 + k0, AsW1);
        gload_lds16(Brow0 + k0, BsW0);
        gload_lds16(Brow1 + k0, BsW1);
        __syncthreads();
        bf16x8 af[4], bf[4];
#pragma unroll
        for (int i = 0; i < 4; ++i) {
            af[i] = *(const bf16x8*)(afp + i * 16 * 32);
            bf[i] = *(const bf16x8*)(bfp + i * 16 * 32);
        }
#pragma unroll
        for (int i = 0; i < 4; ++i)
#pragma unroll
            for (int j = 0; j < 4; ++j)
                acc[i][j] = __builtin_amdgcn_mfma_f32_16x16x32_bf16(af[i], bf[j], acc[i][j], 0, 0, 0);
        __syncthreads();
    }
    const int crow = m0 + wm + quad * 4;
    const int ccol = n0 + wn + l15;
#pragma unroll
    for (int i = 0; i < 4; ++i)
#pragma unroll
        for (int j = 0; j < 4; ++j) {
            f32x4 v = acc[i][j];
#pragma unroll
            for (int r = 0; r < 4; ++r)
                Cf[(size_t)(crow + i * 16 + r) * N + ccol + j * 16] = v[r];
        }
}

extern "C" void kernel_launch(void* const* d_in, const int* in_sizes, int n_in,
                              void* d_out, int out_size, void* d_ws, size_t ws_size,
                              hipStream_t stream) {
    const float* X  = (const float*)d_in[0];
    const float* Wk = (const float*)d_in[1];
    const float* Wq = (const float*)d_in[2];
    const float* Wv = (const float*)d_in[3];
    const float* Wo = (const float*)d_in[4];
    float* ws = (float*)d_ws;
    // float-unit offsets; total 23,592,960 fu = 94.4 MB
    ushort* Xb   = (ushort*)ws;                  // bf16 X [8192,1024]; reused as Yb
    ushort* Qs   = (ushort*)(ws + 4194304);      // bf16 Qs [8192,512]
    ushort* Kb   = (ushort*)(ws + 6291456);      // bf16 K  [8192,512]
    ushort* VT   = (ushort*)(ws + 8388608);      // bf16 VT [32][128][2048]
    ushort* ab   = (ushort*)(ws + 12582912);     // bf16 a  [32][2048][64]
    ushort* aT   = (ushort*)(ws + 14680064);     // bf16 aT [32][64][2048]
    ushort* Pb   = (ushort*)(ws + 16777216);     // bf16 P  [32][2048][64]
    float*  Sb   = ws + 18874368;                // fp32 S  [512][8192]
    ushort* WqkT = (ushort*)(ws + 22020096);     // bf16 [1024][1024]
    ushort* WvT  = (ushort*)(ws + 22544384);     // bf16 [1024][1024]
    ushort* WoT  = (ushort*)(ws + 23068672);     // bf16 [1024][1024]
    ushort* Yb = Xb;
    float* out = (float*)d_out;
    float* mbuf = out;            // stats in d_out (overwritten by final GEMM)
    float* sbuf = out + 32768;

    dim3 blk(256);
    prep_inputs_kernel<<<11264, blk, 0, stream>>>(X, Wq, Wk, Wv, Wo, Xb, WqkT, WvT, WoT);
    qk_gemm<<<dim3(8, 64), blk, 0, stream>>>(Xb, WqkT, Qs, Kb, mbuf, sbuf);
    vt_gemm<<<dim3(8, 64), blk, 0, stream>>>(Xb, WvT, VT);
    prep_scanP_kernel<<<512, blk, 0, stream>>>(Kb, Qs, mbuf, sbuf, ab, aT, Pb);
    chunk_sums_mfma<<<512, blk, 0, stream>>>(aT, VT, Sb);
    chunk_prefix_kernel<<<1024, blk, 0, stream>>>(Sb);
    chunk_out_mfma<<<512, blk, 0, stream>>>(ab, Pb, VT, Sb, Yb);
    mfma_gemm<<<dim3(8, 64), blk, 0, stream>>>(Yb, WoT, out, 8192, 1024, 1024);
}

// Round 8
// 224.557 us; speedup vs baseline: 14.9480x; 1.0845x over previous
//
#include <hip/hip_runtime.h>
#include <hip/hip_bf16.h>

// B=4, T=2048, D=1024, L=512, H=8, Lh=64, Dh=128. Chunks: NC=16 of G=128.
// 6-launch pipeline:
//  1 prep_inputs: X->bf16, W->W^T bf16 (WqkT = [WqT;WkT])
//  2 qkv_gemm:  x<8: [Qs|K]=X@[Wq|Wk] (softmax / chunk-stats epilogues)
//               x>=8: VT[bh][d][t]=(X@Wv)^T via LDS-transpose epilogue
//  3 prep_scan_sums: M,A0 combine; a=exp(K-M), A prefix, P=Qs/A; aT in LDS;
//                    S_c^T[d,l] = V^T @ a via MFMA -> bf16
//  4 chunk_prefix: exclusive prefix of S over chunks (fp32 accum, bf16 store)
//  5 chunk_out_mfma: G^T=A@P^T, mask, Y = Gm@V + P@C0
//  6 mfma_gemm: out = Y@Wo (fp32)

typedef __attribute__((ext_vector_type(8))) short bf16x8;
typedef __attribute__((ext_vector_type(4))) float f32x4;

__device__ inline ushort f2bf(float f) {
    unsigned u = __float_as_uint(f);
    unsigned r = (u + 0x7fff + ((u >> 16) & 1)) >> 16;
    return (ushort)r;
}
__device__ inline float bf2f(ushort h) { return __uint_as_float(((unsigned)h) << 16); }

__device__ inline void gload_lds16(const ushort* g, ushort* l) {
    __builtin_amdgcn_global_load_lds((const __attribute__((address_space(1))) void*)g,
                                     (__attribute__((address_space(3))) void*)l, 16, 0, 0);
}

// blocks [0,8192): X fp32 -> bf16. blocks [8192,11264): weight transpose tiles.
__global__ __launch_bounds__(256) void prep_inputs_kernel(const float* __restrict__ X,
                                                          const float* __restrict__ Wq,
                                                          const float* __restrict__ Wk,
                                                          const float* __restrict__ Wv,
                                                          const float* __restrict__ Wo,
                                                          ushort* __restrict__ Xb,
                                                          ushort* __restrict__ WqkT,
                                                          ushort* __restrict__ WvT,
                                                          ushort* __restrict__ WoT) {
    if (blockIdx.x < 8192) {
        int i = blockIdx.x * 1024 + threadIdx.x * 4;
        float4 v = *(const float4*)(X + i);
        ushort4 o = {f2bf(v.x), f2bf(v.y), f2bf(v.z), f2bf(v.w)};
        *(ushort4*)(Xb + i) = o;
        return;
    }
    __shared__ float s[32][33];
    int t = blockIdx.x - 8192;
    const float* W; ushort* WT; int N, tile, rowoff;
    if (t < 512)       { W = Wq; WT = WqkT; N = 512;  tile = t;        rowoff = 0; }
    else if (t < 1024) { W = Wk; WT = WqkT; N = 512;  tile = t - 512;  rowoff = 512; }
    else if (t < 2048) { W = Wv; WT = WvT;  N = 1024; tile = t - 1024; rowoff = 0; }
    else               { W = Wo; WT = WoT;  N = 1024; tile = t - 2048; rowoff = 0; }
    int tilesX = N >> 5;
    int n0 = (tile % tilesX) * 32, k0 = (tile / tilesX) * 32;
    int tx = threadIdx.x & 31, ty0 = threadIdx.x >> 5;
#pragma unroll
    for (int r = 0; r < 4; ++r) {
        int row = ty0 + r * 8;
        s[row][tx] = W[(size_t)(k0 + row) * N + n0 + tx];
    }
    __syncthreads();
#pragma unroll
    for (int r = 0; r < 4; ++r) {
        int row = ty0 + r * 8;
        WT[(size_t)(rowoff + n0 + row) * 1024 + k0 + tx] = f2bf(s[tx][row]);
    }
}

// Merged QKV GEMM: grid (16,64). x<8: C=[Qs|K] (N=1024), softmax (Q cols) or
// chunk-stats+bf16 K (K cols). x>=8: V with LDS-transposed VT epilogue.
__global__ __launch_bounds__(256) void qkv_gemm(const ushort* __restrict__ A,
                                                const ushort* __restrict__ WqkT,
                                                const ushort* __restrict__ WvT,
                                                ushort* __restrict__ Qb,
                                                ushort* __restrict__ Kbp,
                                                ushort* __restrict__ VT,
                                                float* __restrict__ mbuf,
                                                float* __restrict__ sbuf) {
    __shared__ __align__(16) ushort As[128 * 32];
    __shared__ __align__(16) ushort Bs[128 * 32];
    __shared__ __align__(16) ushort Ts[128 * 136];
    __shared__ float sredM[2][128];
    __shared__ float sredS[2][128];
    const int K = 1024;
    const int tid = threadIdx.x;
    const int w = tid >> 6, lane = tid & 63;
    const int quad = lane >> 4, l15 = lane & 15;
    const bool isQK = blockIdx.x < 8;
    const int nx = isQK ? blockIdx.x : (blockIdx.x - 8);
    const ushort* BT = isQK ? WqkT : WvT;
    const int m0 = blockIdx.y * 128, n0 = nx * 128;
    const int wm = (w & 1) * 64, wn = (w >> 1) * 64;
    f32x4 acc[4][4] = {};
    const int r0 = tid >> 2, kc = (tid & 3) * 8;
    const int r1 = 64 + r0;
    const ushort* Arow0 = A + (size_t)(m0 + r0) * K + kc;
    const ushort* Arow1 = A + (size_t)(m0 + r1) * K + kc;
    const ushort* Brow0 = BT + (size_t)(n0 + r0) * K + kc;
    const ushort* Brow1 = BT + (size_t)(n0 + r1) * K + kc;
    ushort* AsW0 = As + (w * 64) * 8;
    ushort* AsW1 = As + (256 + w * 64) * 8;
    ushort* BsW0 = Bs + (w * 64) * 8;
    ushort* BsW1 = Bs + (256 + w * 64) * 8;
    const ushort* afp = As + (wm + l15) * 32 + quad * 8;
    const ushort* bfp = Bs + (wn + l15) * 32 + quad * 8;
    for (int k0 = 0; k0 < K; k0 += 32) {
        gload_lds16(Arow0 + k0, AsW0);
        gload_lds16(Arow1 + k0, AsW1);
        gload_lds16(Brow0 + k0, BsW0);
        gload_lds16(Brow1 + k0, BsW1);
        __syncthreads();
        bf16x8 af[4], bf[4];
#pragma unroll
        for (int i = 0; i < 4; ++i) {
            af[i] = *(const bf16x8*)(afp + i * 16 * 32);
            bf[i] = *(const bf16x8*)(bfp + i * 16 * 32);
        }
#pragma unroll
        for (int i = 0; i < 4; ++i)
#pragma unroll
            for (int j = 0; j < 4; ++j)
                acc[i][j] = __builtin_amdgcn_mfma_f32_16x16x32_bf16(af[i], bf[j], acc[i][j], 0, 0, 0);
        __syncthreads();
    }
    const int crow = m0 + wm + quad * 4;
    const int ccol = n0 + wn + l15;
    if (!isQK) {
        // VT epilogue: transpose tile through LDS, write 256B-contiguous runs.
#pragma unroll
        for (int i = 0; i < 4; ++i)
#pragma unroll
            for (int j = 0; j < 4; ++j) {
                f32x4 v = acc[i][j];
                int d = wn + j * 16 + l15;
                int t = wm + i * 16 + quad * 4;
                ushort4 o = {f2bf(v[0]), f2bf(v[1]), f2bf(v[2]), f2bf(v[3])};
                *(ushort4*)(Ts + d * 136 + t) = o;
            }
        __syncthreads();
        int b = m0 >> 11, tloc = m0 & 2047, h = n0 >> 7;
        ushort* base = VT + ((size_t)(b * 8 + h) * 128) * 2048 + tloc;
        int kk = tid & 7;
#pragma unroll
        for (int p = 0; p < 4; ++p) {
            int dd = p * 32 + (tid >> 3);
            const uint4* src = (const uint4*)(Ts + dd * 136 + kk * 16);
            uint4* dst = (uint4*)(base + (size_t)dd * 2048 + kk * 16);
            dst[0] = src[0];
            dst[1] = src[1];
        }
        return;
    }
    if (n0 < 512) {
        // softmax per row over this wave's 64-col stripe (= one head)
#pragma unroll
        for (int i = 0; i < 4; ++i)
#pragma unroll
            for (int r = 0; r < 4; ++r) {
                float x0 = acc[i][0][r], x1 = acc[i][1][r];
                float x2 = acc[i][2][r], x3 = acc[i][3][r];
                float m = fmaxf(fmaxf(x0, x1), fmaxf(x2, x3));
#pragma unroll
                for (int off = 1; off < 16; off <<= 1) m = fmaxf(m, __shfl_xor(m, off));
                float e0 = __expf(x0 - m), e1 = __expf(x1 - m);
                float e2 = __expf(x2 - m), e3 = __expf(x3 - m);
                float s = (e0 + e1) + (e2 + e3);
#pragma unroll
                for (int off = 1; off < 16; off <<= 1) s += __shfl_xor(s, off);
                float rs = 1.0f / s;
                acc[i][0][r] = e0 * rs; acc[i][1][r] = e1 * rs;
                acc[i][2][r] = e2 * rs; acc[i][3][r] = e3 * rs;
            }
#pragma unroll
        for (int i = 0; i < 4; ++i)
#pragma unroll
            for (int j = 0; j < 4; ++j) {
                f32x4 v = acc[i][j];
#pragma unroll
                for (int r = 0; r < 4; ++r)
                    Qb[(size_t)(crow + i * 16 + r) * 512 + ccol + j * 16] = f2bf(v[r]);
            }
    } else {
        // chunk stats over this block's 128 rows (= chunk c of batch b)
        int b = blockIdx.y >> 4, c = blockIdx.y & 15;
        float mj[4];
#pragma unroll
        for (int j = 0; j < 4; ++j) {
            float m = -1e30f;
#pragma unroll
            for (int i = 0; i < 4; ++i)
#pragma unroll
                for (int r = 0; r < 4; ++r) m = fmaxf(m, acc[i][j][r]);
            m = fmaxf(m, __shfl_xor(m, 16));
            m = fmaxf(m, __shfl_xor(m, 32));
            mj[j] = m;
        }
        if (quad == 0)
#pragma unroll
            for (int j = 0; j < 4; ++j) sredM[w & 1][(w >> 1) * 64 + j * 16 + l15] = mj[j];
        __syncthreads();
#pragma unroll
        for (int j = 0; j < 4; ++j) {
            int ci = (w >> 1) * 64 + j * 16 + l15;
            float M = fmaxf(sredM[0][ci], sredM[1][ci]);
            float s = 0.f;
#pragma unroll
            for (int i = 0; i < 4; ++i)
#pragma unroll
                for (int r = 0; r < 4; ++r) s += __expf(acc[i][j][r] - M);
            s += __shfl_xor(s, 16);
            s += __shfl_xor(s, 32);
            mj[j] = s;
        }
        if (quad == 0)
#pragma unroll
            for (int j = 0; j < 4; ++j) sredS[w & 1][(w >> 1) * 64 + j * 16 + l15] = mj[j];
        __syncthreads();
        if (tid < 128) {
            int Kcol = (n0 - 512) + tid;
            int h = Kcol >> 6, l = Kcol & 63;
            int idx = (((b * 8 + h) * 16 + c)) * 64 + l;
            mbuf[idx] = fmaxf(sredM[0][tid], sredM[1][tid]);
            sbuf[idx] = sredS[0][tid] + sredS[1][tid];
        }
#pragma unroll
        for (int i = 0; i < 4; ++i)
#pragma unroll
            for (int j = 0; j < 4; ++j) {
                f32x4 v = acc[i][j];
#pragma unroll
                for (int r = 0; r < 4; ++r)
                    Kbp[(size_t)(crow + i * 16 + r) * 512 + (ccol - 512) + j * 16] = f2bf(v[r]);
            }
    }
}

// Block per (bh,c): combine stats -> M,A0; a = exp(K-M); A prefix; P = Qs/A;
// aT kept in LDS; then S_c^T[d,l] = V^T @ a via MFMA, written bf16.
__global__ __launch_bounds__(256) void prep_scan_sums_kernel(const ushort* __restrict__ Kbuf,
                                                             const ushort* __restrict__ Qs,
                                                             const float* __restrict__ mbuf,
                                                             const float* __restrict__ sbuf,
                                                             const ushort* __restrict__ VT,
                                                             ushort* __restrict__ abuf,
                                                             ushort* __restrict__ Pbuf,
                                                             ushort* __restrict__ Sb) {
    __shared__ float red[4][64];
    __shared__ __align__(16) ushort aS[64 * 136];  // [l][t], 272B rows (16B-aligned)
    int blk = blockIdx.x, bh = blk >> 4, c = blk & 15;
    int b = bh >> 3, h = bh & 7;
    int tg = threadIdx.x >> 6, l = threadIdx.x & 63;
    float mc[16];
#pragma unroll
    for (int cc = 0; cc < 16; ++cc) mc[cc] = mbuf[(bh * 16 + cc) * 64 + l];
    float M = -1e30f;
#pragma unroll
    for (int cc = 0; cc < 16; ++cc) M = fmaxf(M, mc[cc]);
    float A0 = 0.f;
    for (int cc = 0; cc < c; ++cc) A0 += sbuf[(bh * 16 + cc) * 64 + l] * __expf(mc[cc] - M);
    const ushort* kp = Kbuf + ((size_t)(b * 2048 + c * 128 + tg * 32)) * 512 + h * 64 + l;
    const ushort* qp = Qs + ((size_t)(b * 2048 + c * 128 + tg * 32)) * 512 + h * 64 + l;
    float a[32];
#pragma unroll
    for (int i = 0; i < 32; ++i) a[i] = __expf(bf2f(kp[(size_t)i * 512]) - M);
    float part = 0.f;
#pragma unroll
    for (int i = 0; i < 32; ++i) part += a[i];
    red[tg][l] = part;
    __syncthreads();
    float A = A0;
    for (int g = 0; g < 4; ++g) {
        float v = red[g][l];
        A += (g < tg) ? v : 0.f;
    }
    ushort* ap = abuf + ((size_t)(bh * 2048 + c * 128 + tg * 32)) * 64 + l;
    ushort* pp = Pbuf + ((size_t)(bh * 2048 + c * 128 + tg * 32)) * 64 + l;
    ushort atmp[32];
#pragma unroll
    for (int i = 0; i < 32; ++i) {
        A += a[i];
        ushort ab16 = f2bf(a[i]);
        ap[(size_t)i * 64] = ab16;
        atmp[i] = ab16;
        pp[(size_t)i * 64] = f2bf(bf2f(qp[(size_t)i * 512]) / A);
    }
    ushort* asp = aS + l * 136 + tg * 32;
#pragma unroll
    for (int v = 0; v < 4; ++v) *(uint4*)(asp + v * 8) = *(const uint4*)(atmp + v * 8);
    __syncthreads();
    // S^T[d,l] = sum_t V^T[d,t] a[t,l]; A-frag from VT (global), B-frag from aS.
    int w = threadIdx.x >> 6, lane = threadIdx.x & 63;
    int quad = lane >> 4, l15 = lane & 15;
    const ushort* vtb = VT + (size_t)bh * 128 * 2048 + c * 128;
    f32x4 acc[2][4] = {};
#pragma unroll
    for (int ks = 0; ks < 4; ++ks) {
        bf16x8 af[2];
#pragma unroll
        for (int mi = 0; mi < 2; ++mi)
            af[mi] = *(const bf16x8*)(vtb + (size_t)(w * 32 + mi * 16 + l15) * 2048 + ks * 32 + quad * 8);
#pragma unroll
        for (int nj = 0; nj < 4; ++nj) {
            bf16x8 bfr = *(const bf16x8*)(aS + (nj * 16 + l15) * 136 + ks * 32 + quad * 8);
#pragma unroll
            for (int mi = 0; mi < 2; ++mi)
                acc[mi][nj] = __builtin_amdgcn_mfma_f32_16x16x32_bf16(af[mi], bfr, acc[mi][nj], 0, 0, 0);
        }
    }
    ushort* sp = Sb + (size_t)blk * 8192;
#pragma unroll
    for (int mi = 0; mi < 2; ++mi)
#pragma unroll
        for (int nj = 0; nj < 4; ++nj) {
            f32x4 v = acc[mi][nj];
#pragma unroll
            for (int r = 0; r < 4; ++r)
                sp[(w * 32 + mi * 16 + quad * 4 + r) * 64 + nj * 16 + l15] = f2bf(v[r]);
        }
}

// In-place exclusive prefix over the 16 chunks; S bf16 [bh][c][d][l], fp32 accum.
__global__ __launch_bounds__(256) void chunk_prefix_kernel(ushort* __restrict__ Sbuf) {
    int gid = blockIdx.x * 256 + threadIdx.x;  // 262144
    int l = gid & 63, d = (gid >> 6) & 127, bh = gid >> 13;
    float run = 0.f;
    for (int c = 0; c < 16; ++c) {
        size_t idx = (size_t)(bh * 16 + c) * 8192 + d * 64 + l;
        float t = bf2f(Sbuf[idx]);
        Sbuf[idx] = f2bf(run);
        run += t;
    }
}

// Per (bh,c): G^T = A @ P^T (C-layout row=s,col=i), mask s<=i, pack to LDS bf16;
// Y = Gm @ V (K=128, b-frag from VT) + P @ C0 (K=64, b-frag from S bf16).
__global__ __launch_bounds__(256) void chunk_out_mfma(const ushort* __restrict__ ab,
                                                      const ushort* __restrict__ Pb,
                                                      const ushort* __restrict__ VT,
                                                      const ushort* __restrict__ S,
                                                      ushort* __restrict__ Yb) {
    __shared__ __align__(16) ushort Gs[128 * 136];  // [i][s], +8 pad kills conflicts
    int blk = blockIdx.x, bh = blk >> 4, c = blk & 15;
    int b = bh >> 3, h = bh & 7;
    int w = threadIdx.x >> 6, lane = threadIdx.x & 63;
    int quad = lane >> 4, l15 = lane & 15;
    const ushort* Pc = Pb + (size_t)(bh * 2048 + c * 128) * 64;
    const ushort* Ac = ab + (size_t)(bh * 2048 + c * 128) * 64;
    // Phase 1: G^T = A @ P^T for cols i in [w*32, w*32+32)
    f32x4 g[8][2] = {};
#pragma unroll
    for (int ks = 0; ks < 2; ++ks) {
        bf16x8 bfr[2];
#pragma unroll
        for (int ni = 0; ni < 2; ++ni)
            bfr[ni] = *(const bf16x8*)(Pc + (w * 32 + ni * 16 + l15) * 64 + ks * 32 + quad * 8);
#pragma unroll
        for (int ms = 0; ms < 8; ++ms) {
            bf16x8 af = *(const bf16x8*)(Ac + (ms * 16 + l15) * 64 + ks * 32 + quad * 8);
#pragma unroll
            for (int ni = 0; ni < 2; ++ni)
                g[ms][ni] = __builtin_amdgcn_mfma_f32_16x16x32_bf16(af, bfr[ni], g[ms][ni], 0, 0, 0);
        }
    }
#pragma unroll
    for (int ms = 0; ms < 8; ++ms)
#pragma unroll
        for (int ni = 0; ni < 2; ++ni) {
            int iL = w * 32 + ni * 16 + l15;
            int sBase = ms * 16 + quad * 4;
            f32x4 v = g[ms][ni];
            ushort4 o;
            o.x = (sBase + 0 <= iL) ? f2bf(v[0]) : (ushort)0;
            o.y = (sBase + 1 <= iL) ? f2bf(v[1]) : (ushort)0;
            o.z = (sBase + 2 <= iL) ? f2bf(v[2]) : (ushort)0;
            o.w = (sBase + 3 <= iL) ? f2bf(v[3]) : (ushort)0;
            *(ushort4*)(Gs + iL * 136 + sBase) = o;
        }
    __syncthreads();
    // Phase 2: Y rows i in [w*32, w*32+32)
    const ushort* vtb = VT + (size_t)bh * 128 * 2048 + c * 128;
    const ushort* sp = S + (size_t)blk * 8192;
    f32x4 y[2][8] = {};
#pragma unroll
    for (int ks = 0; ks < 4; ++ks) {
        bf16x8 af[2];
#pragma unroll
        for (int mi = 0; mi < 2; ++mi)
            af[mi] = *(const bf16x8*)(Gs + (w * 32 + mi * 16 + l15) * 136 + ks * 32 + quad * 8);
#pragma unroll
        for (int nj = 0; nj < 8; ++nj) {
            bf16x8 bfr = *(const bf16x8*)(vtb + (size_t)(nj * 16 + l15) * 2048 + ks * 32 + quad * 8);
#pragma unroll
            for (int mi = 0; mi < 2; ++mi)
                y[mi][nj] = __builtin_amdgcn_mfma_f32_16x16x32_bf16(af[mi], bfr, y[mi][nj], 0, 0, 0);
        }
    }
#pragma unroll
    for (int ks = 0; ks < 2; ++ks) {
        bf16x8 af[2];
#pragma unroll
        for (int mi = 0; mi < 2; ++mi)
            af[mi] = *(const bf16x8*)(Pc + (w * 32 + mi * 16 + l15) * 64 + ks * 32 + quad * 8);
#pragma unroll
        for (int nj = 0; nj < 8; ++nj) {
            bf16x8 bfr = *(const bf16x8*)(sp + (nj * 16 + l15) * 64 + ks * 32 + quad * 8);
#pragma unroll
            for (int mi = 0; mi < 2; ++mi)
                y[mi][nj] = __builtin_amdgcn_mfma_f32_16x16x32_bf16(af[mi], bfr, y[mi][nj], 0, 0, 0);
        }
    }
    ushort* yout = Yb + ((size_t)(b * 2048 + c * 128)) * 1024 + h * 128;
#pragma unroll
    for (int mi = 0; mi < 2; ++mi)
#pragma unroll
        for (int nj = 0; nj < 8; ++nj) {
            f32x4 v = y[mi][nj];
#pragma unroll
            for (int r = 0; r < 4; ++r) {
                int iL = w * 32 + mi * 16 + quad * 4 + r;
                yout[(size_t)iL * 1024 + nj * 16 + l15] = f2bf(v[r]);
            }
        }
}

// Plain GEMM, fp32 C natural (final out = Y @ Wo).
__global__ __launch_bounds__(256) void mfma_gemm(const ushort* __restrict__ A,
                                                 const ushort* __restrict__ BT,
                                                 float* __restrict__ Cf,
                                                 int M, int N, int K) {
    __shared__ __align__(16) ushort As[128 * 32];
    __shared__ __align__(16) ushort Bs[128 * 32];
    const int tid = threadIdx.x;
    const int w = tid >> 6, lane = tid & 63;
    const int quad = lane >> 4, l15 = lane & 15;
    const int m0 = blockIdx.y * 128, n0 = blockIdx.x * 128;
    const int wm = (w & 1) * 64, wn = (w >> 1) * 64;
    f32x4 acc[4][4] = {};
    const int r0 = tid >> 2, kc = (tid & 3) * 8;
    const int r1 = 64 + r0;
    const ushort* Arow0 = A + (size_t)(m0 + r0) * K + kc;
    const ushort* Arow1 = A + (size_t)(m0 + r1) * K + kc;
    const ushort* Brow0 = BT + (size_t)(n0 + r0) * K + kc;
    const ushort* Brow1 = BT + (size_t)(n0 + r1) * K + kc;
    ushort* AsW0 = As + (w * 64) * 8;
    ushort* AsW1 = As + (256 + w * 64) * 8;
    ushort* BsW0 = Bs + (w * 64) * 8;
    ushort* BsW1 = Bs + (256 + w * 64) * 8;
    const ushort* afp = As + (wm + l15) * 32 + quad * 8;
    const ushort* bfp = Bs + (wn + l15) * 32 + quad * 8;
    for (int k0 = 0; k0 < K; k0 += 32) {
        gload_lds16(Arow0 + k0, AsW0);
        gload_lds16(Arow1 + k0, AsW1);
        gload_lds16(Brow0 + k0, BsW0);
        gload_lds16(Brow1 + k0, BsW1);
        __syncthreads();
        bf16x8 af[4], bf[4];
#pragma unroll
        for (int i = 0; i < 4; ++i) {
            af[i] = *(const bf16x8*)(afp + i * 16 * 32);
            bf[i] = *(const bf16x8*)(bfp + i * 16 * 32);
        }
#pragma unroll
        for (int i = 0; i < 4; ++i)
#pragma unroll
            for (int j = 0; j < 4; ++j)
                acc[i][j] = __builtin_amdgcn_mfma_f32_16x16x32_bf16(af[i], bf[j], acc[i][j], 0, 0, 0);
        __syncthreads();
    }
    const int crow = m0 + wm + quad * 4;
    const int ccol = n0 + wn + l15;
#pragma unroll
    for (int i = 0; i < 4; ++i)
#pragma unroll
        for (int j = 0; j < 4; ++j) {
            f32x4 v = acc[i][j];
#pragma unroll
            for (int r = 0; r < 4; ++r)
                Cf[(size_t)(crow + i * 16 + r) * N + ccol + j * 16] = v[r];
        }
}

extern "C" void kernel_launch(void* const* d_in, const int* in_sizes, int n_in,
                              void* d_out, int out_size, void* d_ws, size_t ws_size,
                              hipStream_t stream) {
    const float* X  = (const float*)d_in[0];
    const float* Wk = (const float*)d_in[1];
    const float* Wq = (const float*)d_in[2];
    const float* Wv = (const float*)d_in[3];
    const float* Wo = (const float*)d_in[4];
    float* ws = (float*)d_ws;
    // float-unit offsets; total ~82 MB
    ushort* Xb   = (ushort*)ws;                  // bf16 X [8192,1024]; reused as Yb
    ushort* Qs   = (ushort*)(ws + 4194304);      // bf16 Qs [8192,512]
    ushort* Kb   = (ushort*)(ws + 6291456);      // bf16 K  [8192,512]
    ushort* VT   = (ushort*)(ws + 8388608);      // bf16 VT [32][128][2048]
    ushort* ab   = (ushort*)(ws + 12582912);     // bf16 a  [32][2048][64]
    ushort* Pb   = (ushort*)(ws + 14680064);     // bf16 P  [32][2048][64]
    ushort* Sb   = (ushort*)(ws + 16777216);     // bf16 S  [512][128][64]
    ushort* WqkT = (ushort*)(ws + 18874368);     // bf16 [1024][1024]
    ushort* WvT  = (ushort*)(ws + 19398656);     // bf16 [1024][1024]
    ushort* WoT  = (ushort*)(ws + 19922944);     // bf16 [1024][1024]
    ushort* Yb = Xb;
    float* out = (float*)d_out;
    float* mbuf = out;            // stats in d_out (overwritten by final GEMM)
    float* sbuf = out + 32768;

    dim3 blk(256);
    prep_inputs_kernel<<<11264, blk, 0, stream>>>(X, Wq, Wk, Wv, Wo, Xb, WqkT, WvT, WoT);
    qkv_gemm<<<dim3(16, 64), blk, 0, stream>>>(Xb, WqkT, WvT, Qs, Kb, VT, mbuf, sbuf);
    prep_scan_sums_kernel<<<512, blk, 0, stream>>>(Kb, Qs, mbuf, sbuf, VT, ab, Pb, Sb);
    chunk_prefix_kernel<<<1024, blk, 0, stream>>>(Sb);
    chunk_out_mfma<<<512, blk, 0, stream>>>(ab, Pb, VT, Sb, Yb);
    mfma_gemm<<<dim3(8, 64), blk, 0, stream>>>(Yb, WoT, out, 8192, 1024, 1024);
}